// Round 5
// baseline (2986.025 us; speedup 1.0000x reference)
//
#include <hip/hip_runtime.h>
#include <hip/hip_bf16.h>
#include <hip/hip_fp16.h>

// Renet3d. Matmuls: bf16 MFMA 16x16x32, fp32 accum.
// Scan v5: k-split pair scheme with register-resident weights (as v4), but the pair
// exchange is lock-free message passing: per-wave RELEASE flags + RELAXED agent-scope
// coalesced loads/stores (no RMW atomics), t-parity double-buffered mailbox, and the
// own-half MFMAs + xw prefetch overlap the poll/pull. 2 barriers/step.

typedef __attribute__((ext_vector_type(8))) short bf16x8;
typedef __attribute__((ext_vector_type(4))) float f32x4;
typedef __attribute__((ext_vector_type(4))) unsigned int u32x4;
typedef __attribute__((ext_vector_type(2))) unsigned int u32x2;

#define AGENT __HIP_MEMORY_SCOPE_AGENT

__device__ __forceinline__ unsigned short f2bf(float f) {
    unsigned int u = __float_as_uint(f);
    u += 0x7fffu + ((u >> 16) & 1u);
    return (unsigned short)(u >> 16);
}

// ---------------- weight casts: 9 jobs, optional gate-order row permutation ----------------
struct CastW { const float* src[9]; unsigned short* dst[9]; int n[9]; int L[9]; int perm[9]; };
__global__ void k_castw(CastW j) {
    const int a = blockIdx.y;
    const int i = blockIdx.x * 256 + threadIdx.x;
    if (i >= j.n[a]) return;
    const int L = j.L[a];
    const int r = i >> L, c = i & ((1 << L) - 1);
    const int dr = j.perm[a] ? ((r & 255) * 4 + (r >> 8)) : r;
    j.dst[a][(dr << L) | c] = f2bf(j.src[a][i]);
}
struct CastB { const float* src[4]; float* dst[4]; };
__global__ void k_castb(CastB j) {
    const int a = blockIdx.y;
    const int i = blockIdx.x * 256 + threadIdx.x;   // 0..1023
    j.dst[a][(i & 255) * 4 + (i >> 8)] = j.src[a][i];
}

// ---------------- gather: 5D f32 -> v_in bf16 [512*16][64] ----------------
__global__ void k_gather(const float* __restrict__ X, unsigned short* __restrict__ vin,
                         int sm, int sa, int sb) {
    const int seq = blockIdx.x;              // n*16+a
    const int n = seq >> 4, a = seq & 15;
    const size_t base = (size_t)(n >> 4) * 64 * 4096 + (size_t)sm * (n & 15) + (size_t)sa * a;
    for (int idx = threadIdx.x; idx < 1024; idx += 256) {
        const int c = idx & 63, b = idx >> 6;
        vin[((size_t)seq * 16 + b) * 64 + c] = f2bf(X[base + (size_t)c * 4096 + (size_t)sb * b]);
    }
}

// ---------------- GEMM: C[m][n](f16) = sum_k A[m][k]*W[n][k] + bias[n] ----------------
__global__ __launch_bounds__(256) void k_gemm(const unsigned short* __restrict__ A, int K,
        const unsigned short* __restrict__ W, const float* __restrict__ bias,
        __half* __restrict__ C, int ldc, int nvalid) {
    __shared__ unsigned short Alds[128 * 56];
    __shared__ unsigned short Blds[128 * 56];
    const int m0 = blockIdx.x * 128, n0 = blockIdx.y * 128;
    const int tid = threadIdx.x;
    const int lane = tid & 63, wid = tid >> 6;
    const int wr = wid >> 1, wc = wid & 1;
    const int fl = lane & 15, kk = (lane >> 4) * 8;
    f32x4 acc[4][4];
    #pragma unroll
    for (int mi = 0; mi < 4; mi++)
        #pragma unroll
        for (int ni = 0; ni < 4; ni++) { f32x4 z = {0.f,0.f,0.f,0.f}; acc[mi][ni] = z; }

    for (int k0 = 0; k0 < K; k0 += 32) {
        __syncthreads();
        #pragma unroll
        for (int h = 0; h < 2; h++) {
            const int cid = tid + h * 256;
            const int row = cid >> 2, c4 = cid & 3;
            *(u32x4*)&Alds[row * 56 + c4 * 8] = *(const u32x4*)(A + (size_t)(m0 + row) * K + k0 + c4 * 8);
            *(u32x4*)&Blds[row * 56 + c4 * 8] = *(const u32x4*)(W + (size_t)(n0 + row) * K + k0 + c4 * 8);
        }
        __syncthreads();
        bf16x8 af[4], bfb[4];
        #pragma unroll
        for (int i = 0; i < 4; i++) {
            af[i]  = *(const bf16x8*)&Alds[(wr * 64 + i * 16 + fl) * 56 + kk];
            bfb[i] = *(const bf16x8*)&Blds[(wc * 64 + i * 16 + fl) * 56 + kk];
        }
        #pragma unroll
        for (int mi = 0; mi < 4; mi++)
            #pragma unroll
            for (int ni = 0; ni < 4; ni++)
                acc[mi][ni] = __builtin_amdgcn_mfma_f32_16x16x32_bf16(af[mi], bfb[ni], acc[mi][ni], 0, 0, 0);
    }
    const int rl = (lane >> 4) * 4;
    #pragma unroll
    for (int ni = 0; ni < 4; ni++) {
        const int col = n0 + wc * 64 + ni * 16 + fl;
        if (col < nvalid) {
            const float bs = bias[col];
            #pragma unroll
            for (int mi = 0; mi < 4; mi++) {
                const int row = m0 + wr * 64 + mi * 16 + rl;
                #pragma unroll
                for (int j = 0; j < 4; j++)
                    C[(size_t)(row + j) * ldc + col] = __float2half(acc[mi][ni][j] + bs);
            }
        }
    }
}

// ---------------- LSTM scan v5: register weights + lock-free pair exchange ----------------
// grid (32, 2, 2): x = seq-tile, y = dir, z = kh (k-half). 512 threads (8 waves).
// Wave w owns gate cols [kh*512 + w*64, +64); weights 4nt x 8kk bf16x8 = 128 regs/lane.
// Mailbox HX: [slot][parity][512 u64]; flags FLG: [slot][8 waves], epoch = 32*phase + t + 1.
__global__ __launch_bounds__(512, 2) void k_scan(const __half* __restrict__ xw,
        const unsigned short* __restrict__ whh_f, const unsigned short* __restrict__ whh_b,
        unsigned short* __restrict__ out, int out_mode,
        unsigned long long* __restrict__ HX, unsigned int* __restrict__ FLG, int phase) {
    __shared__ __align__(16) char gbuf[512 * 40];      // gates f16 [512 local cols][20 s-slots]
    __shared__ __align__(16) char hbuf[16 * 512];      // h bf16 [16 s][256 k], XOR-swizzled
    const int tid = threadIdx.x;
    const int lane = tid & 63, w = tid >> 6;
    const int fl = lane & 15, fh = lane >> 4;
    const int st = blockIdx.x, dir = blockIdx.y, kh = blockIdx.z;
    const int seq0 = st * 16;
    const unsigned short* whh_k = (dir ? whh_b : whh_f) + (size_t)kh * 512 * 256;
    const __half* xwd = xw + (size_t)dir * (8192 * 1024);
    const int C0g = kh * 512 + w * 64;
    const int slot = ((dir * 32 + st) * 2 + kh);
    unsigned long long* hx_me = HX + (size_t)slot * 1024;
    const unsigned long long* hx_p = HX + (size_t)(slot ^ 1) * 1024;
    unsigned int* flg_me = FLG + slot * 8;
    const unsigned int* flg_p = FLG + (slot ^ 1) * 8;
    const unsigned int base = 32u * (unsigned int)phase;

    // zero hbuf (h(-1) = 0, both halves)
    #pragma unroll
    for (int i = 0; i < 4; i++) ((unsigned int*)hbuf)[tid + i * 512] = 0u;

    // weights -> registers (once): wave's 64 cols x 256 k
    bf16x8 wreg[4][8];
    #pragma unroll
    for (int nt = 0; nt < 4; nt++)
        #pragma unroll
        for (int kk = 0; kk < 8; kk++)
            wreg[nt][kk] = *(const bf16x8*)(whh_k + (size_t)(w * 64 + nt * 16 + fl) * 256 + kk * 32 + fh * 8);

    const int li = lane & 15, ls = lane >> 4;
    const int khalf = w * 16 + li;               // k within this block's half [0,128)
    const int kglob = kh * 128 + khalf;
    float c_reg[4] = {0.f, 0.f, 0.f, 0.f};

    int tt = dir ? 15 : 0;
    const int tstep = dir ? -1 : 1;

    // prologue: xw C-operands for t=0 (elem (nt,j): seq row fh*4+j, col C0g+nt*16+fl)
    unsigned int xh[4][2];
    #pragma unroll
    for (int nt = 0; nt < 4; nt++)
        #pragma unroll
        for (int j2 = 0; j2 < 2; j2++) {
            const size_t b_ = ((size_t)(seq0 + fh * 4 + j2 * 2) * 16 + tt) * 1024 + C0g + nt * 16 + fl;
            const unsigned short h0 = __half_as_ushort(xwd[b_]);
            const unsigned short h1 = __half_as_ushort(xwd[b_ + 16 * 1024]);
            xh[nt][j2] = (unsigned int)h0 | ((unsigned int)h1 << 16);
        }

    __syncthreads();

    for (int t = 0; t < 16; t++) {
        // ---- copy-out h(t-1) own half (coalesced from hbuf) ----
        if (t > 0) {
            const int ttp = tt - tstep;
            const int s = tid >> 5, q = tid & 31;
            const int ba = (s * 512 + (kh * 128 + q * 4) * 2) ^ ((s & 7) << 4);
            const u32x2 hv = *(const u32x2*)(hbuf + ba);
            const size_t row = out_mode ? ((size_t)(seq0 + s) * 16 + ttp)
                                        : ((size_t)st * 256 + (size_t)ttp * 16 + s);
            *(u32x2*)(out + row * 512 + dir * 256 + kh * 128 + q * 4) = hv;
        }
        // ---- own-half A-frags + own-half MFMAs (no partner dependency) ----
        bf16x8 afr[4];
        #pragma unroll
        for (int i = 0; i < 4; i++) {
            const int kk = kh * 4 + i;
            const int ba = (fl * 512 + kk * 64 + fh * 16) ^ ((fl & 7) << 4);
            afr[i] = *(const bf16x8*)(hbuf + ba);
        }
        f32x4 acc[4];
        #pragma unroll
        for (int nt = 0; nt < 4; nt++) {
            acc[nt][0] = __half2float(__ushort_as_half((unsigned short)(xh[nt][0] & 0xffff)));
            acc[nt][1] = __half2float(__ushort_as_half((unsigned short)(xh[nt][0] >> 16)));
            acc[nt][2] = __half2float(__ushort_as_half((unsigned short)(xh[nt][1] & 0xffff)));
            acc[nt][3] = __half2float(__ushort_as_half((unsigned short)(xh[nt][1] >> 16)));
            #pragma unroll
            for (int i = 0; i < 4; i++)
                acc[nt] = __builtin_amdgcn_mfma_f32_16x16x32_bf16(afr[i], wreg[nt][kh * 4 + i], acc[nt], 0, 0, 0);
        }
        // ---- xw prefetch for t+1 (flies during poll/pull) ----
        const int tn = (t < 15) ? tt + tstep : tt;
        #pragma unroll
        for (int nt = 0; nt < 4; nt++)
            #pragma unroll
            for (int j2 = 0; j2 < 2; j2++) {
                const size_t b_ = ((size_t)(seq0 + fh * 4 + j2 * 2) * 16 + tn) * 1024 + C0g + nt * 16 + fl;
                const unsigned short h0 = __half_as_ushort(xwd[b_]);
                const unsigned short h1 = __half_as_ushort(xwd[b_ + 16 * 1024]);
                xh[nt][j2] = (unsigned int)h0 | ((unsigned int)h1 << 16);
            }
        // ---- poll partner flags, pull partner h(t-1), write into hbuf partner half ----
        if (t > 0) {
            const unsigned int want = base + (unsigned int)t;
            while (true) {
                const unsigned int f = __hip_atomic_load(flg_p + (lane & 7), __ATOMIC_ACQUIRE, AGENT);
                if (__all((int)(f >= want))) break;
                __builtin_amdgcn_s_sleep(2);
            }
            const unsigned long long pv =
                __hip_atomic_load(hx_p + (((t - 1) & 1) * 512 + tid), __ATOMIC_RELAXED, AGENT);
            const int kl = tid >> 2, sl0 = (tid & 3) * 4;
            const int kp = (1 - kh) * 128 + kl;
            #pragma unroll
            for (int e = 0; e < 4; e++) {
                const int s = sl0 + e;
                *(unsigned short*)(hbuf + ((s * 512 + kp * 2) ^ ((s & 7) << 4))) =
                    (unsigned short)(pv >> (16 * e));
            }
        }
        __syncthreads();   // E: partner half in hbuf; all own-half reads done

        // ---- partner-half MFMAs ----
        #pragma unroll
        for (int i = 0; i < 4; i++) {
            const int kk = (1 - kh) * 4 + i;
            const int ba = (fl * 512 + kk * 64 + fh * 16) ^ ((fl & 7) << 4);
            afr[i] = *(const bf16x8*)(hbuf + ba);
        }
        #pragma unroll
        for (int nt = 0; nt < 4; nt++) {
            #pragma unroll
            for (int i = 0; i < 4; i++)
                acc[nt] = __builtin_amdgcn_mfma_f32_16x16x32_bf16(afr[i], wreg[nt][(1 - kh) * 4 + i], acc[nt], 0, 0, 0);
            const int coll = w * 64 + nt * 16 + fl;
            const unsigned int lo = (unsigned int)__half_as_ushort(__float2half(acc[nt][0])) |
                                    ((unsigned int)__half_as_ushort(__float2half(acc[nt][1])) << 16);
            const unsigned int hi = (unsigned int)__half_as_ushort(__float2half(acc[nt][2])) |
                                    ((unsigned int)__half_as_ushort(__float2half(acc[nt][3])) << 16);
            u32x2 pk = {lo, hi};
            *(u32x2*)(gbuf + coll * 40 + fh * 8) = pk;
        }

        // ---- nonlinearity (wave-local gbuf cols) ----
        float gv[4][4];
        const int colbase = w * 64 + 4 * li;
        #pragma unroll
        for (int g = 0; g < 4; g++) {
            const u32x2 a = *(const u32x2*)(gbuf + (colbase + g) * 40 + ls * 8);
            gv[g][0] = __half2float(__ushort_as_half((unsigned short)(a[0] & 0xffff)));
            gv[g][1] = __half2float(__ushort_as_half((unsigned short)(a[0] >> 16)));
            gv[g][2] = __half2float(__ushort_as_half((unsigned short)(a[1] & 0xffff)));
            gv[g][3] = __half2float(__ushort_as_half((unsigned short)(a[1] >> 16)));
        }
        unsigned long long hpack = 0ull;
        #pragma unroll
        for (int p2 = 0; p2 < 4; p2++) {
            const float ig = 1.f / (1.f + __expf(-gv[0][p2]));
            const float fg = 1.f / (1.f + __expf(-gv[1][p2]));
            const float e2 = __expf(2.f * gv[2][p2]);
            const float gg = 1.f - 2.f / (e2 + 1.f);
            const float og = 1.f / (1.f + __expf(-gv[3][p2]));
            const float c = fg * c_reg[p2] + ig * gg;
            c_reg[p2] = c;
            const float e2c = __expf(2.f * c);
            const float hv = og * (1.f - 2.f / (e2c + 1.f));
            const unsigned short hb = f2bf(hv);
            const int s = ls * 4 + p2;
            *(unsigned short*)(hbuf + ((s * 512 + kglob * 2) ^ ((s & 7) << 4))) = hb;
            hpack |= ((unsigned long long)hb) << (16 * p2);
        }

        // ---- publish own h(t): per-wave data stores + per-wave RELEASE flag ----
        if (t < 15) {
            __hip_atomic_store(hx_me + ((t & 1) * 512 + khalf * 4 + ls), hpack, __ATOMIC_RELAXED, AGENT);
            if (lane == 0)
                __hip_atomic_store(flg_me + w, base + (unsigned int)(t + 1), __ATOMIC_RELEASE, AGENT);
        }
        tt = tn;
        __syncthreads();   // F: hbuf(t) complete for next step's readers
    }
    // epilogue: copy-out h(15) own half
    {
        const int s = tid >> 5, q = tid & 31;
        const int ba = (s * 512 + (kh * 128 + q * 4) * 2) ^ ((s & 7) << 4);
        const u32x2 hv = *(const u32x2*)(hbuf + ba);
        const size_t row = out_mode ? ((size_t)(seq0 + s) * 16 + tt)
                                    : ((size_t)st * 256 + (size_t)tt * 16 + s);
        *(u32x2*)(out + row * 512 + dir * 256 + kh * 128 + q * 4) = hv;
    }
}

// ---------------- conv2 scatter: f16 conv output -> 5D f32 ----------------
__global__ void k_scatter(const __half* __restrict__ conv, float* __restrict__ Xout,
                          int sm, int sa, int sb) {
    const int blk = blockIdx.x;
    const int n = blk >> 4, a = blk & 15;
    const size_t base = (size_t)(n >> 4) * 64 * 4096 + (size_t)sm * (n & 15) + (size_t)sa * a;
    for (int idx = threadIdx.x; idx < 1024; idx += 256) {
        const int b = idx & 15, o = idx >> 4;
        Xout[base + (size_t)o * 4096 + (size_t)sb * b] =
            __half2float(conv[((size_t)(n * 16 + b) * 16 + a) * 64 + o]);
    }
}

// ---------------- final conv3d 1x1x1 (f32 vector) ----------------
__global__ __launch_bounds__(256) void k_conv3(const float* __restrict__ X,
        const float* __restrict__ w, const float* __restrict__ bias, float* __restrict__ out) {
    __shared__ float xl[64 * 32];
    __shared__ float wl[64 * 64];
    const int bb = blockIdx.y;
    const int p0 = blockIdx.x * 32;
    const int tid = threadIdx.x;
    for (int i = tid; i < 64 * 32; i += 256) {
        const int c = i >> 5, pp = i & 31;
        xl[i] = X[((size_t)bb * 64 + c) * 4096 + p0 + pp];
    }
    for (int i = tid; i < 64 * 64; i += 256) wl[i] = w[i];
    __syncthreads();
    const int pp = tid & 31, og = tid >> 5;
    #pragma unroll
    for (int oj = 0; oj < 8; oj++) {
        const int o = og * 8 + oj;
        float acc = bias[o];
        #pragma unroll 16
        for (int c = 0; c < 64; c++) acc += xl[c * 32 + pp] * wl[o * 64 + c];
        out[((size_t)bb * 64 + o) * 4096 + p0 + pp] = acc;
    }
}

extern "C" void kernel_launch(void* const* d_in, const int* in_sizes, int n_in,
                              void* d_out, int out_size, void* d_ws, size_t ws_size,
                              hipStream_t stream) {
    (void)in_sizes; (void)n_in; (void)out_size; (void)ws_size;
    const float* x     = (const float*)d_in[0];
    const float* vwihf = (const float*)d_in[1];
    const float* vwhhf = (const float*)d_in[2];
    const float* vbf   = (const float*)d_in[3];
    const float* vwihb = (const float*)d_in[4];
    const float* vwhhb = (const float*)d_in[5];
    const float* vbb   = (const float*)d_in[6];
    const float* hwihf = (const float*)d_in[7];
    const float* hwhhf = (const float*)d_in[8];
    const float* hbf   = (const float*)d_in[9];
    const float* hwihb = (const float*)d_in[10];
    const float* hwhhb = (const float*)d_in[11];
    const float* hbb   = (const float*)d_in[12];
    const float* c2w   = (const float*)d_in[13];
    const float* c2b   = (const float*)d_in[14];
    const float* c3w   = (const float*)d_in[15];
    const float* c3b   = (const float*)d_in[16];

    char* p = (char*)d_ws;
    auto alloc = [&](size_t bytes) { char* r = p; p += (bytes + 255) & ~((size_t)255); return r; };
    unsigned short* bVWIHf = (unsigned short*)alloc((size_t)1024 * 64 * 2);
    unsigned short* bVWIHb = (unsigned short*)alloc((size_t)1024 * 64 * 2);
    unsigned short* bVWHHf = (unsigned short*)alloc((size_t)1024 * 256 * 2);
    unsigned short* bVWHHb = (unsigned short*)alloc((size_t)1024 * 256 * 2);
    unsigned short* bHWIHf = (unsigned short*)alloc((size_t)1024 * 512 * 2);
    unsigned short* bHWIHb = (unsigned short*)alloc((size_t)1024 * 512 * 2);
    unsigned short* bHWHHf = (unsigned short*)alloc((size_t)1024 * 256 * 2);
    unsigned short* bHWHHb = (unsigned short*)alloc((size_t)1024 * 256 * 2);
    unsigned short* bC2W   = (unsigned short*)alloc((size_t)128 * 512 * 2);
    float* pVBf = (float*)alloc(1024 * 4);
    float* pVBb = (float*)alloc(1024 * 4);
    float* pHBf = (float*)alloc(1024 * 4);
    float* pHBb = (float*)alloc(1024 * 4);
    unsigned long long* HX = (unsigned long long*)alloc((size_t)128 * 8192);  // [128 slots][2][512] u64
    unsigned int* FLG = (unsigned int*)alloc(4096);                           // [128 slots][8 waves]
    float* XA = (float*)alloc((size_t)524288 * 4);
    float* XB = (float*)alloc((size_t)524288 * 4);
    unsigned short* VIN = (unsigned short*)alloc((size_t)8192 * 64 * 2);
    __half* XW = (__half*)alloc((size_t)2 * 8192 * 1024 * 2);
    unsigned short* S_   = (unsigned short*)alloc((size_t)8192 * 512 * 2);
    unsigned short* HOUT = (unsigned short*)alloc((size_t)8192 * 512 * 2);
    __half* CONV = (__half*)VIN;   // reuse (dead by conv time)

    hipMemsetAsync(bC2W, 0, (size_t)128 * 512 * 2, stream);
    hipMemsetAsync(FLG, 0, 4096, stream);   // epoch reset once per launch (in-graph, replay-safe)
    CastW cw;
    const float* srcs[9] = {vwihf, vwihb, vwhhf, vwhhb, hwihf, hwihb, hwhhf, hwhhb, c2w};
    unsigned short* dsts[9] = {bVWIHf, bVWIHb, bVWHHf, bVWHHb, bHWIHf, bHWIHb, bHWHHf, bHWHHb, bC2W};
    const int ns[9] = {65536, 65536, 262144, 262144, 524288, 524288, 262144, 262144, 32768};
    const int Ls[9] = {6, 6, 8, 8, 9, 9, 8, 8, 9};
    const int pm[9] = {1, 1, 1, 1, 1, 1, 1, 1, 0};
    for (int i = 0; i < 9; i++) { cw.src[i] = srcs[i]; cw.dst[i] = dsts[i]; cw.n[i] = ns[i]; cw.L[i] = Ls[i]; cw.perm[i] = pm[i]; }
    k_castw<<<dim3(2048, 9), 256, 0, stream>>>(cw);
    CastB cb;
    cb.src[0] = vbf; cb.dst[0] = pVBf;
    cb.src[1] = vbb; cb.dst[1] = pVBb;
    cb.src[2] = hbf; cb.dst[2] = pHBf;
    cb.src[3] = hbb; cb.dst[3] = pHBb;
    k_castb<<<dim3(4, 4), 256, 0, stream>>>(cb);

    const int SMs[3] = {256, 16, 1}, SAs[3] = {16, 256, 256}, SBs[3] = {1, 1, 16};
    for (int s = 0; s < 3; s++) {
        const float* Xin = (s == 0) ? x : ((s == 1) ? XA : XB);
        float* Xout = (s == 0) ? XA : ((s == 1) ? XB : XA);
        k_gather<<<512, 256, 0, stream>>>(Xin, VIN, SMs[s], SAs[s], SBs[s]);
        k_gemm<<<dim3(64, 8), 256, 0, stream>>>(VIN, 64, bVWIHf, pVBf, XW, 1024, 1024);
        k_gemm<<<dim3(64, 8), 256, 0, stream>>>(VIN, 64, bVWIHb, pVBb, XW + (size_t)8192 * 1024, 1024, 1024);
        k_scan<<<dim3(32, 2, 2), 512, 0, stream>>>(XW, bVWHHf, bVWHHb, S_, 0, HX, FLG, s * 2 + 0);
        k_gemm<<<dim3(64, 8), 256, 0, stream>>>(S_, 512, bHWIHf, pHBf, XW, 1024, 1024);
        k_gemm<<<dim3(64, 8), 256, 0, stream>>>(S_, 512, bHWIHb, pHBb, XW + (size_t)8192 * 1024, 1024, 1024);
        k_scan<<<dim3(32, 2, 2), 512, 0, stream>>>(XW, bHWHHf, bHWHHb, HOUT, 1, HX, FLG, s * 2 + 1);
        k_gemm<<<dim3(64, 1), 256, 0, stream>>>(HOUT, 512, bC2W, c2b, CONV, 64, 64);
        k_scatter<<<512, 256, 0, stream>>>(CONV, Xout, SMs[s], SAs[s], SBs[s]);
    }
    k_conv3<<<dim3(128, 2), 256, 0, stream>>>(XA, c3w, c3b, (float*)d_out);
}

// Round 6
// 2353.270 us; speedup vs baseline: 1.2689x; 1.2689x over previous
//
#include <hip/hip_runtime.h>
#include <hip/hip_bf16.h>
#include <hip/hip_fp16.h>

// Renet3d. Matmuls: bf16 MFMA 16x16x32, fp32 accum.
// Scan v6 = v5 structure with the rule-#20 fix: weight registers split into
// wown/wpar at LOAD time so kh (blockIdx.z) never appears as a register index.
// Lock-free pair exchange: per-wave RELEASE flags + RELAXED agent-scope coalesced
// mailbox, parity double-buffer, own-half MFMA + xw prefetch overlap the poll.

typedef __attribute__((ext_vector_type(8))) short bf16x8;
typedef __attribute__((ext_vector_type(4))) float f32x4;
typedef __attribute__((ext_vector_type(4))) unsigned int u32x4;
typedef __attribute__((ext_vector_type(2))) unsigned int u32x2;

#define AGENT __HIP_MEMORY_SCOPE_AGENT

__device__ __forceinline__ unsigned short f2bf(float f) {
    unsigned int u = __float_as_uint(f);
    u += 0x7fffu + ((u >> 16) & 1u);
    return (unsigned short)(u >> 16);
}

// ---------------- weight casts: 9 jobs, optional gate-order row permutation ----------------
struct CastW { const float* src[9]; unsigned short* dst[9]; int n[9]; int L[9]; int perm[9]; };
__global__ void k_castw(CastW j) {
    const int a = blockIdx.y;
    const int i = blockIdx.x * 256 + threadIdx.x;
    if (i >= j.n[a]) return;
    const int L = j.L[a];
    const int r = i >> L, c = i & ((1 << L) - 1);
    const int dr = j.perm[a] ? ((r & 255) * 4 + (r >> 8)) : r;
    j.dst[a][(dr << L) | c] = f2bf(j.src[a][i]);
}
struct CastB { const float* src[4]; float* dst[4]; };
__global__ void k_castb(CastB j) {
    const int a = blockIdx.y;
    const int i = blockIdx.x * 256 + threadIdx.x;   // 0..1023
    j.dst[a][(i & 255) * 4 + (i >> 8)] = j.src[a][i];
}

// ---------------- gather: 5D f32 -> v_in bf16 [512*16][64] ----------------
__global__ void k_gather(const float* __restrict__ X, unsigned short* __restrict__ vin,
                         int sm, int sa, int sb) {
    const int seq = blockIdx.x;              // n*16+a
    const int n = seq >> 4, a = seq & 15;
    const size_t base = (size_t)(n >> 4) * 64 * 4096 + (size_t)sm * (n & 15) + (size_t)sa * a;
    for (int idx = threadIdx.x; idx < 1024; idx += 256) {
        const int c = idx & 63, b = idx >> 6;
        vin[((size_t)seq * 16 + b) * 64 + c] = f2bf(X[base + (size_t)c * 4096 + (size_t)sb * b]);
    }
}

// ---------------- GEMM: C[m][n](f16) = sum_k A[m][k]*W[n][k] + bias[n] ----------------
__global__ __launch_bounds__(256) void k_gemm(const unsigned short* __restrict__ A, int K,
        const unsigned short* __restrict__ W, const float* __restrict__ bias,
        __half* __restrict__ C, int ldc, int nvalid) {
    __shared__ unsigned short Alds[128 * 56];
    __shared__ unsigned short Blds[128 * 56];
    const int m0 = blockIdx.x * 128, n0 = blockIdx.y * 128;
    const int tid = threadIdx.x;
    const int lane = tid & 63, wid = tid >> 6;
    const int wr = wid >> 1, wc = wid & 1;
    const int fl = lane & 15, kk = (lane >> 4) * 8;
    f32x4 acc[4][4];
    #pragma unroll
    for (int mi = 0; mi < 4; mi++)
        #pragma unroll
        for (int ni = 0; ni < 4; ni++) { f32x4 z = {0.f,0.f,0.f,0.f}; acc[mi][ni] = z; }

    for (int k0 = 0; k0 < K; k0 += 32) {
        __syncthreads();
        #pragma unroll
        for (int h = 0; h < 2; h++) {
            const int cid = tid + h * 256;
            const int row = cid >> 2, c4 = cid & 3;
            *(u32x4*)&Alds[row * 56 + c4 * 8] = *(const u32x4*)(A + (size_t)(m0 + row) * K + k0 + c4 * 8);
            *(u32x4*)&Blds[row * 56 + c4 * 8] = *(const u32x4*)(W + (size_t)(n0 + row) * K + k0 + c4 * 8);
        }
        __syncthreads();
        bf16x8 af[4], bfb[4];
        #pragma unroll
        for (int i = 0; i < 4; i++) {
            af[i]  = *(const bf16x8*)&Alds[(wr * 64 + i * 16 + fl) * 56 + kk];
            bfb[i] = *(const bf16x8*)&Blds[(wc * 64 + i * 16 + fl) * 56 + kk];
        }
        #pragma unroll
        for (int mi = 0; mi < 4; mi++)
            #pragma unroll
            for (int ni = 0; ni < 4; ni++)
                acc[mi][ni] = __builtin_amdgcn_mfma_f32_16x16x32_bf16(af[mi], bfb[ni], acc[mi][ni], 0, 0, 0);
    }
    const int rl = (lane >> 4) * 4;
    #pragma unroll
    for (int ni = 0; ni < 4; ni++) {
        const int col = n0 + wc * 64 + ni * 16 + fl;
        if (col < nvalid) {
            const float bs = bias[col];
            #pragma unroll
            for (int mi = 0; mi < 4; mi++) {
                const int row = m0 + wr * 64 + mi * 16 + rl;
                #pragma unroll
                for (int j = 0; j < 4; j++)
                    C[(size_t)(row + j) * ldc + col] = __float2half(acc[mi][ni][j] + bs);
            }
        }
    }
}

// ---------------- LSTM scan v6: register weights + lock-free pair exchange ----------------
// grid (32, 2, 2): x = seq-tile, y = dir, z = kh (k-half). 512 threads (8 waves).
// Wave w owns gate cols [kh*512 + w*64, +64). Weights: wown/wpar 4nt x 4 bf16x8 each
// (128 regs/lane total), ALL register indices compile-time (rule #20).
__global__ __launch_bounds__(512, 2) void k_scan(const __half* __restrict__ xw,
        const unsigned short* __restrict__ whh_f, const unsigned short* __restrict__ whh_b,
        unsigned short* __restrict__ out, int out_mode,
        unsigned long long* __restrict__ HX, unsigned int* __restrict__ FLG, int phase) {
    __shared__ __align__(16) char gbuf[512 * 40];      // gates f16 [512 local cols][20 s-slots]
    __shared__ __align__(16) char hbuf[16 * 512];      // h bf16 [16 s][256 k], XOR-swizzled
    const int tid = threadIdx.x;
    const int lane = tid & 63, w = tid >> 6;
    const int fl = lane & 15, fh = lane >> 4;
    const int st = blockIdx.x, dir = blockIdx.y, kh = blockIdx.z;
    const int seq0 = st * 16;
    const unsigned short* whh_k = (dir ? whh_b : whh_f) + (size_t)kh * 512 * 256;
    const __half* xwd = xw + (size_t)dir * (8192 * 1024);
    const int C0g = kh * 512 + w * 64;
    const int slot = ((dir * 32 + st) * 2 + kh);
    unsigned long long* hx_me = HX + (size_t)slot * 1024;
    const unsigned long long* hx_p = HX + (size_t)(slot ^ 1) * 1024;
    unsigned int* flg_me = FLG + slot * 8;
    const unsigned int* flg_p = FLG + (slot ^ 1) * 8;
    const unsigned int base = 32u * (unsigned int)phase;
    const int kOwnB = kh * 4;          // runtime — used in ADDRESSES only
    const int kParB = (1 - kh) * 4;    // runtime — used in ADDRESSES only

    // zero hbuf (h(-1) = 0, both halves)
    #pragma unroll
    for (int i = 0; i < 4; i++) ((unsigned int*)hbuf)[tid + i * 512] = 0u;

    // weights -> registers (once). wown = this block's k-half, wpar = partner's k-half.
    // Register indices are compile-time; kh only affects the load address.
    bf16x8 wown[4][4], wpar[4][4];
    #pragma unroll
    for (int nt = 0; nt < 4; nt++) {
        const unsigned short* rowp = whh_k + (size_t)(w * 64 + nt * 16 + fl) * 256 + fh * 8;
        #pragma unroll
        for (int i = 0; i < 4; i++) {
            wown[nt][i] = *(const bf16x8*)(rowp + (kOwnB + i) * 32);
            wpar[nt][i] = *(const bf16x8*)(rowp + (kParB + i) * 32);
        }
    }

    const int li = lane & 15, ls = lane >> 4;
    const int khalf = w * 16 + li;               // k within this block's half [0,128)
    const int kglob = kh * 128 + khalf;
    float c_reg[4] = {0.f, 0.f, 0.f, 0.f};

    int tt = dir ? 15 : 0;
    const int tstep = dir ? -1 : 1;

    // prologue: xw C-operands for t=0 (elem (nt,j): seq row fh*4+j, col C0g+nt*16+fl)
    unsigned int xh[4][2];
    #pragma unroll
    for (int nt = 0; nt < 4; nt++)
        #pragma unroll
        for (int j2 = 0; j2 < 2; j2++) {
            const size_t b_ = ((size_t)(seq0 + fh * 4 + j2 * 2) * 16 + tt) * 1024 + C0g + nt * 16 + fl;
            const unsigned short h0 = __half_as_ushort(xwd[b_]);
            const unsigned short h1 = __half_as_ushort(xwd[b_ + 16 * 1024]);
            xh[nt][j2] = (unsigned int)h0 | ((unsigned int)h1 << 16);
        }

    __syncthreads();

    for (int t = 0; t < 16; t++) {
        // ---- copy-out h(t-1) own half (coalesced from hbuf) ----
        if (t > 0) {
            const int ttp = tt - tstep;
            const int s = tid >> 5, q = tid & 31;
            const int ba = (s * 512 + (kh * 128 + q * 4) * 2) ^ ((s & 7) << 4);
            const u32x2 hv = *(const u32x2*)(hbuf + ba);
            const size_t row = out_mode ? ((size_t)(seq0 + s) * 16 + ttp)
                                        : ((size_t)st * 256 + (size_t)ttp * 16 + s);
            *(u32x2*)(out + row * 512 + dir * 256 + kh * 128 + q * 4) = hv;
        }
        // ---- own-half A-frags + own-half MFMAs (no partner dependency) ----
        bf16x8 afr[4];
        #pragma unroll
        for (int i = 0; i < 4; i++) {
            const int ba = (fl * 512 + (kOwnB + i) * 64 + fh * 16) ^ ((fl & 7) << 4);
            afr[i] = *(const bf16x8*)(hbuf + ba);
        }
        f32x4 acc[4];
        #pragma unroll
        for (int nt = 0; nt < 4; nt++) {
            acc[nt][0] = __half2float(__ushort_as_half((unsigned short)(xh[nt][0] & 0xffff)));
            acc[nt][1] = __half2float(__ushort_as_half((unsigned short)(xh[nt][0] >> 16)));
            acc[nt][2] = __half2float(__ushort_as_half((unsigned short)(xh[nt][1] & 0xffff)));
            acc[nt][3] = __half2float(__ushort_as_half((unsigned short)(xh[nt][1] >> 16)));
            #pragma unroll
            for (int i = 0; i < 4; i++)
                acc[nt] = __builtin_amdgcn_mfma_f32_16x16x32_bf16(afr[i], wown[nt][i], acc[nt], 0, 0, 0);
        }
        // ---- xw prefetch for t+1 (flies during poll/pull) ----
        const int tn = (t < 15) ? tt + tstep : tt;
        #pragma unroll
        for (int nt = 0; nt < 4; nt++)
            #pragma unroll
            for (int j2 = 0; j2 < 2; j2++) {
                const size_t b_ = ((size_t)(seq0 + fh * 4 + j2 * 2) * 16 + tn) * 1024 + C0g + nt * 16 + fl;
                const unsigned short h0 = __half_as_ushort(xwd[b_]);
                const unsigned short h1 = __half_as_ushort(xwd[b_ + 16 * 1024]);
                xh[nt][j2] = (unsigned int)h0 | ((unsigned int)h1 << 16);
            }
        // ---- poll partner flags, pull partner h(t-1), write into hbuf partner half ----
        if (t > 0) {
            const unsigned int want = base + (unsigned int)t;
            while (true) {
                const unsigned int f = __hip_atomic_load(flg_p + (lane & 7), __ATOMIC_ACQUIRE, AGENT);
                if (__all((int)(f >= want))) break;
                __builtin_amdgcn_s_sleep(2);
            }
            const unsigned long long pv =
                __hip_atomic_load(hx_p + (((t - 1) & 1) * 512 + tid), __ATOMIC_RELAXED, AGENT);
            const int kl = tid >> 2, sl0 = (tid & 3) * 4;
            const int kp = (1 - kh) * 128 + kl;
            #pragma unroll
            for (int e = 0; e < 4; e++) {
                const int s = sl0 + e;
                *(unsigned short*)(hbuf + ((s * 512 + kp * 2) ^ ((s & 7) << 4))) =
                    (unsigned short)(pv >> (16 * e));
            }
        }
        __syncthreads();   // E: partner half in hbuf; all own-half reads done

        // ---- partner-half MFMAs ----
        #pragma unroll
        for (int i = 0; i < 4; i++) {
            const int ba = (fl * 512 + (kParB + i) * 64 + fh * 16) ^ ((fl & 7) << 4);
            afr[i] = *(const bf16x8*)(hbuf + ba);
        }
        #pragma unroll
        for (int nt = 0; nt < 4; nt++) {
            #pragma unroll
            for (int i = 0; i < 4; i++)
                acc[nt] = __builtin_amdgcn_mfma_f32_16x16x32_bf16(afr[i], wpar[nt][i], acc[nt], 0, 0, 0);
            const int coll = w * 64 + nt * 16 + fl;
            const unsigned int lo = (unsigned int)__half_as_ushort(__float2half(acc[nt][0])) |
                                    ((unsigned int)__half_as_ushort(__float2half(acc[nt][1])) << 16);
            const unsigned int hi = (unsigned int)__half_as_ushort(__float2half(acc[nt][2])) |
                                    ((unsigned int)__half_as_ushort(__float2half(acc[nt][3])) << 16);
            u32x2 pk = {lo, hi};
            *(u32x2*)(gbuf + coll * 40 + fh * 8) = pk;
        }

        // ---- nonlinearity (wave-local gbuf cols) ----
        float gv[4][4];
        const int colbase = w * 64 + 4 * li;
        #pragma unroll
        for (int g = 0; g < 4; g++) {
            const u32x2 a = *(const u32x2*)(gbuf + (colbase + g) * 40 + ls * 8);
            gv[g][0] = __half2float(__ushort_as_half((unsigned short)(a[0] & 0xffff)));
            gv[g][1] = __half2float(__ushort_as_half((unsigned short)(a[0] >> 16)));
            gv[g][2] = __half2float(__ushort_as_half((unsigned short)(a[1] & 0xffff)));
            gv[g][3] = __half2float(__ushort_as_half((unsigned short)(a[1] >> 16)));
        }
        unsigned long long hpack = 0ull;
        #pragma unroll
        for (int p2 = 0; p2 < 4; p2++) {
            const float ig = 1.f / (1.f + __expf(-gv[0][p2]));
            const float fg = 1.f / (1.f + __expf(-gv[1][p2]));
            const float e2 = __expf(2.f * gv[2][p2]);
            const float gg = 1.f - 2.f / (e2 + 1.f);
            const float og = 1.f / (1.f + __expf(-gv[3][p2]));
            const float c = fg * c_reg[p2] + ig * gg;
            c_reg[p2] = c;
            const float e2c = __expf(2.f * c);
            const float hv = og * (1.f - 2.f / (e2c + 1.f));
            const unsigned short hb = f2bf(hv);
            const int s = ls * 4 + p2;
            *(unsigned short*)(hbuf + ((s * 512 + kglob * 2) ^ ((s & 7) << 4))) = hb;
            hpack |= ((unsigned long long)hb) << (16 * p2);
        }

        // ---- publish own h(t): per-wave data stores + per-wave RELEASE flag ----
        if (t < 15) {
            __hip_atomic_store(hx_me + ((t & 1) * 512 + khalf * 4 + ls), hpack, __ATOMIC_RELAXED, AGENT);
            if (lane == 0)
                __hip_atomic_store(flg_me + w, base + (unsigned int)(t + 1), __ATOMIC_RELEASE, AGENT);
        }
        tt = tn;
        __syncthreads();   // F: hbuf(t) complete for next step's readers
    }
    // epilogue: copy-out h(15) own half
    {
        const int s = tid >> 5, q = tid & 31;
        const int ba = (s * 512 + (kh * 128 + q * 4) * 2) ^ ((s & 7) << 4);
        const u32x2 hv = *(const u32x2*)(hbuf + ba);
        const size_t row = out_mode ? ((size_t)(seq0 + s) * 16 + tt)
                                    : ((size_t)st * 256 + (size_t)tt * 16 + s);
        *(u32x2*)(out + row * 512 + dir * 256 + kh * 128 + q * 4) = hv;
    }
}

// ---------------- conv2 scatter: f16 conv output -> 5D f32 ----------------
__global__ void k_scatter(const __half* __restrict__ conv, float* __restrict__ Xout,
                          int sm, int sa, int sb) {
    const int blk = blockIdx.x;
    const int n = blk >> 4, a = blk & 15;
    const size_t base = (size_t)(n >> 4) * 64 * 4096 + (size_t)sm * (n & 15) + (size_t)sa * a;
    for (int idx = threadIdx.x; idx < 1024; idx += 256) {
        const int b = idx & 15, o = idx >> 4;
        Xout[base + (size_t)o * 4096 + (size_t)sb * b] =
            __half2float(conv[((size_t)(n * 16 + b) * 16 + a) * 64 + o]);
    }
}

// ---------------- final conv3d 1x1x1 (f32 vector) ----------------
__global__ __launch_bounds__(256) void k_conv3(const float* __restrict__ X,
        const float* __restrict__ w, const float* __restrict__ bias, float* __restrict__ out) {
    __shared__ float xl[64 * 32];
    __shared__ float wl[64 * 64];
    const int bb = blockIdx.y;
    const int p0 = blockIdx.x * 32;
    const int tid = threadIdx.x;
    for (int i = tid; i < 64 * 32; i += 256) {
        const int c = i >> 5, pp = i & 31;
        xl[i] = X[((size_t)bb * 64 + c) * 4096 + p0 + pp];
    }
    for (int i = tid; i < 64 * 64; i += 256) wl[i] = w[i];
    __syncthreads();
    const int pp = tid & 31, og = tid >> 5;
    #pragma unroll
    for (int oj = 0; oj < 8; oj++) {
        const int o = og * 8 + oj;
        float acc = bias[o];
        #pragma unroll 16
        for (int c = 0; c < 64; c++) acc += xl[c * 32 + pp] * wl[o * 64 + c];
        out[((size_t)bb * 64 + o) * 4096 + p0 + pp] = acc;
    }
}

extern "C" void kernel_launch(void* const* d_in, const int* in_sizes, int n_in,
                              void* d_out, int out_size, void* d_ws, size_t ws_size,
                              hipStream_t stream) {
    (void)in_sizes; (void)n_in; (void)out_size; (void)ws_size;
    const float* x     = (const float*)d_in[0];
    const float* vwihf = (const float*)d_in[1];
    const float* vwhhf = (const float*)d_in[2];
    const float* vbf   = (const float*)d_in[3];
    const float* vwihb = (const float*)d_in[4];
    const float* vwhhb = (const float*)d_in[5];
    const float* vbb   = (const float*)d_in[6];
    const float* hwihf = (const float*)d_in[7];
    const float* hwhhf = (const float*)d_in[8];
    const float* hbf   = (const float*)d_in[9];
    const float* hwihb = (const float*)d_in[10];
    const float* hwhhb = (const float*)d_in[11];
    const float* hbb   = (const float*)d_in[12];
    const float* c2w   = (const float*)d_in[13];
    const float* c2b   = (const float*)d_in[14];
    const float* c3w   = (const float*)d_in[15];
    const float* c3b   = (const float*)d_in[16];

    char* p = (char*)d_ws;
    auto alloc = [&](size_t bytes) { char* r = p; p += (bytes + 255) & ~((size_t)255); return r; };
    unsigned short* bVWIHf = (unsigned short*)alloc((size_t)1024 * 64 * 2);
    unsigned short* bVWIHb = (unsigned short*)alloc((size_t)1024 * 64 * 2);
    unsigned short* bVWHHf = (unsigned short*)alloc((size_t)1024 * 256 * 2);
    unsigned short* bVWHHb = (unsigned short*)alloc((size_t)1024 * 256 * 2);
    unsigned short* bHWIHf = (unsigned short*)alloc((size_t)1024 * 512 * 2);
    unsigned short* bHWIHb = (unsigned short*)alloc((size_t)1024 * 512 * 2);
    unsigned short* bHWHHf = (unsigned short*)alloc((size_t)1024 * 256 * 2);
    unsigned short* bHWHHb = (unsigned short*)alloc((size_t)1024 * 256 * 2);
    unsigned short* bC2W   = (unsigned short*)alloc((size_t)128 * 512 * 2);
    float* pVBf = (float*)alloc(1024 * 4);
    float* pVBb = (float*)alloc(1024 * 4);
    float* pHBf = (float*)alloc(1024 * 4);
    float* pHBb = (float*)alloc(1024 * 4);
    unsigned long long* HX = (unsigned long long*)alloc((size_t)128 * 8192);  // [128 slots][2][512] u64
    unsigned int* FLG = (unsigned int*)alloc(4096);                           // [128 slots][8 waves]
    float* XA = (float*)alloc((size_t)524288 * 4);
    float* XB = (float*)alloc((size_t)524288 * 4);
    unsigned short* VIN = (unsigned short*)alloc((size_t)8192 * 64 * 2);
    __half* XW = (__half*)alloc((size_t)2 * 8192 * 1024 * 2);
    unsigned short* S_   = (unsigned short*)alloc((size_t)8192 * 512 * 2);
    unsigned short* HOUT = (unsigned short*)alloc((size_t)8192 * 512 * 2);
    __half* CONV = (__half*)VIN;   // reuse (dead by conv time)

    hipMemsetAsync(bC2W, 0, (size_t)128 * 512 * 2, stream);
    hipMemsetAsync(FLG, 0, 4096, stream);   // epoch reset once per launch (in-graph, replay-safe)
    CastW cw;
    const float* srcs[9] = {vwihf, vwihb, vwhhf, vwhhb, hwihf, hwihb, hwhhf, hwhhb, c2w};
    unsigned short* dsts[9] = {bVWIHf, bVWIHb, bVWHHf, bVWHHb, bHWIHf, bHWIHb, bHWHHf, bHWHHb, bC2W};
    const int ns[9] = {65536, 65536, 262144, 262144, 524288, 524288, 262144, 262144, 32768};
    const int Ls[9] = {6, 6, 8, 8, 9, 9, 8, 8, 9};
    const int pm[9] = {1, 1, 1, 1, 1, 1, 1, 1, 0};
    for (int i = 0; i < 9; i++) { cw.src[i] = srcs[i]; cw.dst[i] = dsts[i]; cw.n[i] = ns[i]; cw.L[i] = Ls[i]; cw.perm[i] = pm[i]; }
    k_castw<<<dim3(2048, 9), 256, 0, stream>>>(cw);
    CastB cb;
    cb.src[0] = vbf; cb.dst[0] = pVBf;
    cb.src[1] = vbb; cb.dst[1] = pVBb;
    cb.src[2] = hbf; cb.dst[2] = pHBf;
    cb.src[3] = hbb; cb.dst[3] = pHBb;
    k_castb<<<dim3(4, 4), 256, 0, stream>>>(cb);

    const int SMs[3] = {256, 16, 1}, SAs[3] = {16, 256, 256}, SBs[3] = {1, 1, 16};
    for (int s = 0; s < 3; s++) {
        const float* Xin = (s == 0) ? x : ((s == 1) ? XA : XB);
        float* Xout = (s == 0) ? XA : ((s == 1) ? XB : XA);
        k_gather<<<512, 256, 0, stream>>>(Xin, VIN, SMs[s], SAs[s], SBs[s]);
        k_gemm<<<dim3(64, 8), 256, 0, stream>>>(VIN, 64, bVWIHf, pVBf, XW, 1024, 1024);
        k_gemm<<<dim3(64, 8), 256, 0, stream>>>(VIN, 64, bVWIHb, pVBb, XW + (size_t)8192 * 1024, 1024, 1024);
        k_scan<<<dim3(32, 2, 2), 512, 0, stream>>>(XW, bVWHHf, bVWHHb, S_, 0, HX, FLG, s * 2 + 0);
        k_gemm<<<dim3(64, 8), 256, 0, stream>>>(S_, 512, bHWIHf, pHBf, XW, 1024, 1024);
        k_gemm<<<dim3(64, 8), 256, 0, stream>>>(S_, 512, bHWIHb, pHBb, XW + (size_t)8192 * 1024, 1024, 1024);
        k_scan<<<dim3(32, 2, 2), 512, 0, stream>>>(XW, bHWHHf, bHWHHb, HOUT, 1, HX, FLG, s * 2 + 1);
        k_gemm<<<dim3(64, 1), 256, 0, stream>>>(HOUT, 512, bC2W, c2b, CONV, 64, 64);
        k_scatter<<<512, 256, 0, stream>>>(CONV, Xout, SMs[s], SAs[s], SBs[s]);
    }
    k_conv3<<<dim3(128, 2), 256, 0, stream>>>(XA, c3w, c3b, (float*)d_out);
}

// Round 7
// 2029.274 us; speedup vs baseline: 1.4715x; 1.1597x over previous
//
#include <hip/hip_runtime.h>
#include <hip/hip_bf16.h>
#include <hip/hip_fp16.h>

// Renet3d. Matmuls: bf16 MFMA 16x16x32, fp32 accum.
// Scan v7 = v6 with the poll fixed: RELAXED flag polling (no per-iteration
// vmcnt-drain / L1-invalidate) + ONE acquire fence after the poll exits.
// Register-resident whh halves (wown/wpar, compile-time indices only),
// lock-free pair exchange via parity-double-buffered mailbox.

typedef __attribute__((ext_vector_type(8))) short bf16x8;
typedef __attribute__((ext_vector_type(4))) float f32x4;
typedef __attribute__((ext_vector_type(4))) unsigned int u32x4;
typedef __attribute__((ext_vector_type(2))) unsigned int u32x2;

#define AGENT __HIP_MEMORY_SCOPE_AGENT

__device__ __forceinline__ unsigned short f2bf(float f) {
    unsigned int u = __float_as_uint(f);
    u += 0x7fffu + ((u >> 16) & 1u);
    return (unsigned short)(u >> 16);
}

// ---------------- weight casts: 9 jobs, optional gate-order row permutation ----------------
struct CastW { const float* src[9]; unsigned short* dst[9]; int n[9]; int L[9]; int perm[9]; };
__global__ void k_castw(CastW j) {
    const int a = blockIdx.y;
    const int i = blockIdx.x * 256 + threadIdx.x;
    if (i >= j.n[a]) return;
    const int L = j.L[a];
    const int r = i >> L, c = i & ((1 << L) - 1);
    const int dr = j.perm[a] ? ((r & 255) * 4 + (r >> 8)) : r;
    j.dst[a][(dr << L) | c] = f2bf(j.src[a][i]);
}
struct CastB { const float* src[4]; float* dst[4]; };
__global__ void k_castb(CastB j) {
    const int a = blockIdx.y;
    const int i = blockIdx.x * 256 + threadIdx.x;   // 0..1023
    j.dst[a][(i & 255) * 4 + (i >> 8)] = j.src[a][i];
}

// ---------------- gather: 5D f32 -> v_in bf16 [512*16][64] ----------------
__global__ void k_gather(const float* __restrict__ X, unsigned short* __restrict__ vin,
                         int sm, int sa, int sb) {
    const int seq = blockIdx.x;              // n*16+a
    const int n = seq >> 4, a = seq & 15;
    const size_t base = (size_t)(n >> 4) * 64 * 4096 + (size_t)sm * (n & 15) + (size_t)sa * a;
    for (int idx = threadIdx.x; idx < 1024; idx += 256) {
        const int c = idx & 63, b = idx >> 6;
        vin[((size_t)seq * 16 + b) * 64 + c] = f2bf(X[base + (size_t)c * 4096 + (size_t)sb * b]);
    }
}

// ---------------- GEMM: C[m][n](f16) = sum_k A[m][k]*W[n][k] + bias[n] ----------------
__global__ __launch_bounds__(256) void k_gemm(const unsigned short* __restrict__ A, int K,
        const unsigned short* __restrict__ W, const float* __restrict__ bias,
        __half* __restrict__ C, int ldc, int nvalid) {
    __shared__ unsigned short Alds[128 * 56];
    __shared__ unsigned short Blds[128 * 56];
    const int m0 = blockIdx.x * 128, n0 = blockIdx.y * 128;
    const int tid = threadIdx.x;
    const int lane = tid & 63, wid = tid >> 6;
    const int wr = wid >> 1, wc = wid & 1;
    const int fl = lane & 15, kk = (lane >> 4) * 8;
    f32x4 acc[4][4];
    #pragma unroll
    for (int mi = 0; mi < 4; mi++)
        #pragma unroll
        for (int ni = 0; ni < 4; ni++) { f32x4 z = {0.f,0.f,0.f,0.f}; acc[mi][ni] = z; }

    for (int k0 = 0; k0 < K; k0 += 32) {
        __syncthreads();
        #pragma unroll
        for (int h = 0; h < 2; h++) {
            const int cid = tid + h * 256;
            const int row = cid >> 2, c4 = cid & 3;
            *(u32x4*)&Alds[row * 56 + c4 * 8] = *(const u32x4*)(A + (size_t)(m0 + row) * K + k0 + c4 * 8);
            *(u32x4*)&Blds[row * 56 + c4 * 8] = *(const u32x4*)(W + (size_t)(n0 + row) * K + k0 + c4 * 8);
        }
        __syncthreads();
        bf16x8 af[4], bfb[4];
        #pragma unroll
        for (int i = 0; i < 4; i++) {
            af[i]  = *(const bf16x8*)&Alds[(wr * 64 + i * 16 + fl) * 56 + kk];
            bfb[i] = *(const bf16x8*)&Blds[(wc * 64 + i * 16 + fl) * 56 + kk];
        }
        #pragma unroll
        for (int mi = 0; mi < 4; mi++)
            #pragma unroll
            for (int ni = 0; ni < 4; ni++)
                acc[mi][ni] = __builtin_amdgcn_mfma_f32_16x16x32_bf16(af[mi], bfb[ni], acc[mi][ni], 0, 0, 0);
    }
    const int rl = (lane >> 4) * 4;
    #pragma unroll
    for (int ni = 0; ni < 4; ni++) {
        const int col = n0 + wc * 64 + ni * 16 + fl;
        if (col < nvalid) {
            const float bs = bias[col];
            #pragma unroll
            for (int mi = 0; mi < 4; mi++) {
                const int row = m0 + wr * 64 + mi * 16 + rl;
                #pragma unroll
                for (int j = 0; j < 4; j++)
                    C[(size_t)(row + j) * ldc + col] = __float2half(acc[mi][ni][j] + bs);
            }
        }
    }
}

// ---------------- LSTM scan v7: register weights + lock-free pair exchange ----------------
// grid (32, 2, 2): x = seq-tile, y = dir, z = kh (k-half). 512 threads (8 waves).
// Wave w owns gate cols [kh*512 + w*64, +64). Weights wown/wpar: 4nt x 4 bf16x8 each,
// all register indices compile-time. Mailbox HX [slot][parity][512 u64];
// flags FLG [slot][8 waves], epoch = 32*phase + t + 1.
__global__ __launch_bounds__(512, 2) void k_scan(const __half* __restrict__ xw,
        const unsigned short* __restrict__ whh_f, const unsigned short* __restrict__ whh_b,
        unsigned short* __restrict__ out, int out_mode,
        unsigned long long* __restrict__ HX, unsigned int* __restrict__ FLG, int phase) {
    __shared__ __align__(16) char gbuf[512 * 40];      // gates f16 [512 local cols][20 s-slots]
    __shared__ __align__(16) char hbuf[16 * 512];      // h bf16 [16 s][256 k], XOR-swizzled
    const int tid = threadIdx.x;
    const int lane = tid & 63, w = tid >> 6;
    const int fl = lane & 15, fh = lane >> 4;
    const int st = blockIdx.x, dir = blockIdx.y, kh = blockIdx.z;
    const int seq0 = st * 16;
    const unsigned short* whh_k = (dir ? whh_b : whh_f) + (size_t)kh * 512 * 256;
    const __half* xwd = xw + (size_t)dir * (8192 * 1024);
    const int C0g = kh * 512 + w * 64;
    const int slot = ((dir * 32 + st) * 2 + kh);
    unsigned long long* hx_me = HX + (size_t)slot * 1024;
    const unsigned long long* hx_p = HX + (size_t)(slot ^ 1) * 1024;
    unsigned int* flg_me = FLG + slot * 8;
    const unsigned int* flg_p = FLG + (slot ^ 1) * 8;
    const unsigned int base = 32u * (unsigned int)phase;
    const int kOwnB = kh * 4;          // runtime — used in ADDRESSES only
    const int kParB = (1 - kh) * 4;    // runtime — used in ADDRESSES only

    // zero hbuf (h(-1) = 0, both halves)
    #pragma unroll
    for (int i = 0; i < 4; i++) ((unsigned int*)hbuf)[tid + i * 512] = 0u;

    // weights -> registers (once). kh only affects the load ADDRESS.
    bf16x8 wown[4][4], wpar[4][4];
    #pragma unroll
    for (int nt = 0; nt < 4; nt++) {
        const unsigned short* rowp = whh_k + (size_t)(w * 64 + nt * 16 + fl) * 256 + fh * 8;
        #pragma unroll
        for (int i = 0; i < 4; i++) {
            wown[nt][i] = *(const bf16x8*)(rowp + (kOwnB + i) * 32);
            wpar[nt][i] = *(const bf16x8*)(rowp + (kParB + i) * 32);
        }
    }

    const int li = lane & 15, ls = lane >> 4;
    const int khalf = w * 16 + li;               // k within this block's half [0,128)
    const int kglob = kh * 128 + khalf;
    float c_reg[4] = {0.f, 0.f, 0.f, 0.f};

    int tt = dir ? 15 : 0;
    const int tstep = dir ? -1 : 1;

    // prologue: xw C-operands for t=0 (elem (nt,j): seq row fh*4+j, col C0g+nt*16+fl)
    unsigned int xh[4][2];
    #pragma unroll
    for (int nt = 0; nt < 4; nt++)
        #pragma unroll
        for (int j2 = 0; j2 < 2; j2++) {
            const size_t b_ = ((size_t)(seq0 + fh * 4 + j2 * 2) * 16 + tt) * 1024 + C0g + nt * 16 + fl;
            const unsigned short h0 = __half_as_ushort(xwd[b_]);
            const unsigned short h1 = __half_as_ushort(xwd[b_ + 16 * 1024]);
            xh[nt][j2] = (unsigned int)h0 | ((unsigned int)h1 << 16);
        }

    __syncthreads();

    for (int t = 0; t < 16; t++) {
        // ---- copy-out h(t-1) own half (coalesced from hbuf) ----
        if (t > 0) {
            const int ttp = tt - tstep;
            const int s = tid >> 5, q = tid & 31;
            const int ba = (s * 512 + (kh * 128 + q * 4) * 2) ^ ((s & 7) << 4);
            const u32x2 hv = *(const u32x2*)(hbuf + ba);
            const size_t row = out_mode ? ((size_t)(seq0 + s) * 16 + ttp)
                                        : ((size_t)st * 256 + (size_t)ttp * 16 + s);
            *(u32x2*)(out + row * 512 + dir * 256 + kh * 128 + q * 4) = hv;
        }
        // ---- own-half A-frags + own-half MFMAs (no partner dependency) ----
        bf16x8 afr[4];
        #pragma unroll
        for (int i = 0; i < 4; i++) {
            const int ba = (fl * 512 + (kOwnB + i) * 64 + fh * 16) ^ ((fl & 7) << 4);
            afr[i] = *(const bf16x8*)(hbuf + ba);
        }
        f32x4 acc[4];
        #pragma unroll
        for (int nt = 0; nt < 4; nt++) {
            acc[nt][0] = __half2float(__ushort_as_half((unsigned short)(xh[nt][0] & 0xffff)));
            acc[nt][1] = __half2float(__ushort_as_half((unsigned short)(xh[nt][0] >> 16)));
            acc[nt][2] = __half2float(__ushort_as_half((unsigned short)(xh[nt][1] & 0xffff)));
            acc[nt][3] = __half2float(__ushort_as_half((unsigned short)(xh[nt][1] >> 16)));
            #pragma unroll
            for (int i = 0; i < 4; i++)
                acc[nt] = __builtin_amdgcn_mfma_f32_16x16x32_bf16(afr[i], wown[nt][i], acc[nt], 0, 0, 0);
        }
        // ---- xw prefetch for t+1 (flies during poll/pull) ----
        const int tn = (t < 15) ? tt + tstep : tt;
        #pragma unroll
        for (int nt = 0; nt < 4; nt++)
            #pragma unroll
            for (int j2 = 0; j2 < 2; j2++) {
                const size_t b_ = ((size_t)(seq0 + fh * 4 + j2 * 2) * 16 + tn) * 1024 + C0g + nt * 16 + fl;
                const unsigned short h0 = __half_as_ushort(xwd[b_]);
                const unsigned short h1 = __half_as_ushort(xwd[b_ + 16 * 1024]);
                xh[nt][j2] = (unsigned int)h0 | ((unsigned int)h1 << 16);
            }
        // ---- poll partner flags (RELAXED: no drain/inv per iter), one acquire fence, pull ----
        if (t > 0) {
            const unsigned int want = base + (unsigned int)t;
            while (true) {
                const unsigned int f = __hip_atomic_load(flg_p + (lane & 7), __ATOMIC_RELAXED, AGENT);
                if (__all((int)(f >= want))) break;
                __builtin_amdgcn_s_sleep(1);
            }
            __builtin_amdgcn_fence(__ATOMIC_ACQUIRE, "agent");
            const unsigned long long pv =
                __hip_atomic_load(hx_p + (((t - 1) & 1) * 512 + tid), __ATOMIC_RELAXED, AGENT);
            const int kl = tid >> 2, sl0 = (tid & 3) * 4;
            const int kp = (1 - kh) * 128 + kl;
            #pragma unroll
            for (int e = 0; e < 4; e++) {
                const int s = sl0 + e;
                *(unsigned short*)(hbuf + ((s * 512 + kp * 2) ^ ((s & 7) << 4))) =
                    (unsigned short)(pv >> (16 * e));
            }
        }
        __syncthreads();   // E: partner half in hbuf; all own-half reads done

        // ---- partner-half MFMAs ----
        #pragma unroll
        for (int i = 0; i < 4; i++) {
            const int ba = (fl * 512 + (kParB + i) * 64 + fh * 16) ^ ((fl & 7) << 4);
            afr[i] = *(const bf16x8*)(hbuf + ba);
        }
        #pragma unroll
        for (int nt = 0; nt < 4; nt++) {
            #pragma unroll
            for (int i = 0; i < 4; i++)
                acc[nt] = __builtin_amdgcn_mfma_f32_16x16x32_bf16(afr[i], wpar[nt][i], acc[nt], 0, 0, 0);
            const int coll = w * 64 + nt * 16 + fl;
            const unsigned int lo = (unsigned int)__half_as_ushort(__float2half(acc[nt][0])) |
                                    ((unsigned int)__half_as_ushort(__float2half(acc[nt][1])) << 16);
            const unsigned int hi = (unsigned int)__half_as_ushort(__float2half(acc[nt][2])) |
                                    ((unsigned int)__half_as_ushort(__float2half(acc[nt][3])) << 16);
            u32x2 pk = {lo, hi};
            *(u32x2*)(gbuf + coll * 40 + fh * 8) = pk;
        }

        // ---- nonlinearity (wave-local gbuf cols) ----
        float gv[4][4];
        const int colbase = w * 64 + 4 * li;
        #pragma unroll
        for (int g = 0; g < 4; g++) {
            const u32x2 a = *(const u32x2*)(gbuf + (colbase + g) * 40 + ls * 8);
            gv[g][0] = __half2float(__ushort_as_half((unsigned short)(a[0] & 0xffff)));
            gv[g][1] = __half2float(__ushort_as_half((unsigned short)(a[0] >> 16)));
            gv[g][2] = __half2float(__ushort_as_half((unsigned short)(a[1] & 0xffff)));
            gv[g][3] = __half2float(__ushort_as_half((unsigned short)(a[1] >> 16)));
        }
        unsigned long long hpack = 0ull;
        #pragma unroll
        for (int p2 = 0; p2 < 4; p2++) {
            const float ig = 1.f / (1.f + __expf(-gv[0][p2]));
            const float fg = 1.f / (1.f + __expf(-gv[1][p2]));
            const float e2 = __expf(2.f * gv[2][p2]);
            const float gg = 1.f - 2.f / (e2 + 1.f);
            const float og = 1.f / (1.f + __expf(-gv[3][p2]));
            const float c = fg * c_reg[p2] + ig * gg;
            c_reg[p2] = c;
            const float e2c = __expf(2.f * c);
            const float hv = og * (1.f - 2.f / (e2c + 1.f));
            const unsigned short hb = f2bf(hv);
            const int s = ls * 4 + p2;
            *(unsigned short*)(hbuf + ((s * 512 + kglob * 2) ^ ((s & 7) << 4))) = hb;
            hpack |= ((unsigned long long)hb) << (16 * p2);
        }

        // ---- publish own h(t): per-wave data stores + per-wave RELEASE flag ----
        if (t < 15) {
            __hip_atomic_store(hx_me + ((t & 1) * 512 + khalf * 4 + ls), hpack, __ATOMIC_RELAXED, AGENT);
            if (lane == 0)
                __hip_atomic_store(flg_me + w, base + (unsigned int)(t + 1), __ATOMIC_RELEASE, AGENT);
        }
        tt = tn;
        __syncthreads();   // F: hbuf(t) complete for next step's readers
    }
    // epilogue: copy-out h(15) own half
    {
        const int s = tid >> 5, q = tid & 31;
        const int ba = (s * 512 + (kh * 128 + q * 4) * 2) ^ ((s & 7) << 4);
        const u32x2 hv = *(const u32x2*)(hbuf + ba);
        const size_t row = out_mode ? ((size_t)(seq0 + s) * 16 + tt)
                                    : ((size_t)st * 256 + (size_t)tt * 16 + s);
        *(u32x2*)(out + row * 512 + dir * 256 + kh * 128 + q * 4) = hv;
    }
}

// ---------------- conv2 scatter: f16 conv output -> 5D f32 ----------------
__global__ void k_scatter(const __half* __restrict__ conv, float* __restrict__ Xout,
                          int sm, int sa, int sb) {
    const int blk = blockIdx.x;
    const int n = blk >> 4, a = blk & 15;
    const size_t base = (size_t)(n >> 4) * 64 * 4096 + (size_t)sm * (n & 15) + (size_t)sa * a;
    for (int idx = threadIdx.x; idx < 1024; idx += 256) {
        const int b = idx & 15, o = idx >> 4;
        Xout[base + (size_t)o * 4096 + (size_t)sb * b] =
            __half2float(conv[((size_t)(n * 16 + b) * 16 + a) * 64 + o]);
    }
}

// ---------------- final conv3d 1x1x1 (f32 vector) ----------------
__global__ __launch_bounds__(256) void k_conv3(const float* __restrict__ X,
        const float* __restrict__ w, const float* __restrict__ bias, float* __restrict__ out) {
    __shared__ float xl[64 * 32];
    __shared__ float wl[64 * 64];
    const int bb = blockIdx.y;
    const int p0 = blockIdx.x * 32;
    const int tid = threadIdx.x;
    for (int i = tid; i < 64 * 32; i += 256) {
        const int c = i >> 5, pp = i & 31;
        xl[i] = X[((size_t)bb * 64 + c) * 4096 + p0 + pp];
    }
    for (int i = tid; i < 64 * 64; i += 256) wl[i] = w[i];
    __syncthreads();
    const int pp = tid & 31, og = tid >> 5;
    #pragma unroll
    for (int oj = 0; oj < 8; oj++) {
        const int o = og * 8 + oj;
        float acc = bias[o];
        #pragma unroll 16
        for (int c = 0; c < 64; c++) acc += xl[c * 32 + pp] * wl[o * 64 + c];
        out[((size_t)bb * 64 + o) * 4096 + p0 + pp] = acc;
    }
}

extern "C" void kernel_launch(void* const* d_in, const int* in_sizes, int n_in,
                              void* d_out, int out_size, void* d_ws, size_t ws_size,
                              hipStream_t stream) {
    (void)in_sizes; (void)n_in; (void)out_size; (void)ws_size;
    const float* x     = (const float*)d_in[0];
    const float* vwihf = (const float*)d_in[1];
    const float* vwhhf = (const float*)d_in[2];
    const float* vbf   = (const float*)d_in[3];
    const float* vwihb = (const float*)d_in[4];
    const float* vwhhb = (const float*)d_in[5];
    const float* vbb   = (const float*)d_in[6];
    const float* hwihf = (const float*)d_in[7];
    const float* hwhhf = (const float*)d_in[8];
    const float* hbf   = (const float*)d_in[9];
    const float* hwihb = (const float*)d_in[10];
    const float* hwhhb = (const float*)d_in[11];
    const float* hbb   = (const float*)d_in[12];
    const float* c2w   = (const float*)d_in[13];
    const float* c2b   = (const float*)d_in[14];
    const float* c3w   = (const float*)d_in[15];
    const float* c3b   = (const float*)d_in[16];

    char* p = (char*)d_ws;
    auto alloc = [&](size_t bytes) { char* r = p; p += (bytes + 255) & ~((size_t)255); return r; };
    unsigned short* bVWIHf = (unsigned short*)alloc((size_t)1024 * 64 * 2);
    unsigned short* bVWIHb = (unsigned short*)alloc((size_t)1024 * 64 * 2);
    unsigned short* bVWHHf = (unsigned short*)alloc((size_t)1024 * 256 * 2);
    unsigned short* bVWHHb = (unsigned short*)alloc((size_t)1024 * 256 * 2);
    unsigned short* bHWIHf = (unsigned short*)alloc((size_t)1024 * 512 * 2);
    unsigned short* bHWIHb = (unsigned short*)alloc((size_t)1024 * 512 * 2);
    unsigned short* bHWHHf = (unsigned short*)alloc((size_t)1024 * 256 * 2);
    unsigned short* bHWHHb = (unsigned short*)alloc((size_t)1024 * 256 * 2);
    unsigned short* bC2W   = (unsigned short*)alloc((size_t)128 * 512 * 2);
    float* pVBf = (float*)alloc(1024 * 4);
    float* pVBb = (float*)alloc(1024 * 4);
    float* pHBf = (float*)alloc(1024 * 4);
    float* pHBb = (float*)alloc(1024 * 4);
    unsigned long long* HX = (unsigned long long*)alloc((size_t)128 * 8192);  // [128 slots][2][512] u64
    unsigned int* FLG = (unsigned int*)alloc(4096);                           // [128 slots][8 waves]
    float* XA = (float*)alloc((size_t)524288 * 4);
    float* XB = (float*)alloc((size_t)524288 * 4);
    unsigned short* VIN = (unsigned short*)alloc((size_t)8192 * 64 * 2);
    __half* XW = (__half*)alloc((size_t)2 * 8192 * 1024 * 2);
    unsigned short* S_   = (unsigned short*)alloc((size_t)8192 * 512 * 2);
    unsigned short* HOUT = (unsigned short*)alloc((size_t)8192 * 512 * 2);
    __half* CONV = (__half*)VIN;   // reuse (dead by conv time)

    hipMemsetAsync(bC2W, 0, (size_t)128 * 512 * 2, stream);
    hipMemsetAsync(FLG, 0, 4096, stream);   // epoch reset once per launch (in-graph, replay-safe)
    CastW cw;
    const float* srcs[9] = {vwihf, vwihb, vwhhf, vwhhb, hwihf, hwihb, hwhhf, hwhhb, c2w};
    unsigned short* dsts[9] = {bVWIHf, bVWIHb, bVWHHf, bVWHHb, bHWIHf, bHWIHb, bHWHHf, bHWHHb, bC2W};
    const int ns[9] = {65536, 65536, 262144, 262144, 524288, 524288, 262144, 262144, 32768};
    const int Ls[9] = {6, 6, 8, 8, 9, 9, 8, 8, 9};
    const int pm[9] = {1, 1, 1, 1, 1, 1, 1, 1, 0};
    for (int i = 0; i < 9; i++) { cw.src[i] = srcs[i]; cw.dst[i] = dsts[i]; cw.n[i] = ns[i]; cw.L[i] = Ls[i]; cw.perm[i] = pm[i]; }
    k_castw<<<dim3(2048, 9), 256, 0, stream>>>(cw);
    CastB cb;
    cb.src[0] = vbf; cb.dst[0] = pVBf;
    cb.src[1] = vbb; cb.dst[1] = pVBb;
    cb.src[2] = hbf; cb.dst[2] = pHBf;
    cb.src[3] = hbb; cb.dst[3] = pHBb;
    k_castb<<<dim3(4, 4), 256, 0, stream>>>(cb);

    const int SMs[3] = {256, 16, 1}, SAs[3] = {16, 256, 256}, SBs[3] = {1, 1, 16};
    for (int s = 0; s < 3; s++) {
        const float* Xin = (s == 0) ? x : ((s == 1) ? XA : XB);
        float* Xout = (s == 0) ? XA : ((s == 1) ? XB : XA);
        k_gather<<<512, 256, 0, stream>>>(Xin, VIN, SMs[s], SAs[s], SBs[s]);
        k_gemm<<<dim3(64, 8), 256, 0, stream>>>(VIN, 64, bVWIHf, pVBf, XW, 1024, 1024);
        k_gemm<<<dim3(64, 8), 256, 0, stream>>>(VIN, 64, bVWIHb, pVBb, XW + (size_t)8192 * 1024, 1024, 1024);
        k_scan<<<dim3(32, 2, 2), 512, 0, stream>>>(XW, bVWHHf, bVWHHb, S_, 0, HX, FLG, s * 2 + 0);
        k_gemm<<<dim3(64, 8), 256, 0, stream>>>(S_, 512, bHWIHf, pHBf, XW, 1024, 1024);
        k_gemm<<<dim3(64, 8), 256, 0, stream>>>(S_, 512, bHWIHb, pHBb, XW + (size_t)8192 * 1024, 1024, 1024);
        k_scan<<<dim3(32, 2, 2), 512, 0, stream>>>(XW, bHWHHf, bHWHHb, HOUT, 1, HX, FLG, s * 2 + 1);
        k_gemm<<<dim3(64, 1), 256, 0, stream>>>(HOUT, 512, bC2W, c2b, CONV, 64, 64);
        k_scatter<<<512, 256, 0, stream>>>(CONV, Xout, SMs[s], SAs[s], SBs[s]);
    }
    k_conv3<<<dim3(128, 2), 256, 0, stream>>>(XA, c3w, c3b, (float*)d_out);
}

// Round 8
// 593.312 us; speedup vs baseline: 5.0328x; 3.4202x over previous
//
#include <hip/hip_runtime.h>
#include <hip/hip_bf16.h>
#include <hip/hip_fp16.h>

// Renet3d. Matmuls: bf16 MFMA 16x16x32, fp32 accum.
// Scan v8 = v4's proven single-poller handshake + padded per-slot flags (no false
// sharing) + parallel relaxed sc1 mailbox pull (no RMW serialization) + parity
// double-buffered mailbox + v7's own-half-MFMA/prefetch overlap ahead of the poll.
// Register-resident whh halves (wown/wpar, compile-time register indices only).

typedef __attribute__((ext_vector_type(8))) short bf16x8;
typedef __attribute__((ext_vector_type(4))) float f32x4;
typedef __attribute__((ext_vector_type(4))) unsigned int u32x4;
typedef __attribute__((ext_vector_type(2))) unsigned int u32x2;

#define AGENT __HIP_MEMORY_SCOPE_AGENT

__device__ __forceinline__ unsigned short f2bf(float f) {
    unsigned int u = __float_as_uint(f);
    u += 0x7fffu + ((u >> 16) & 1u);
    return (unsigned short)(u >> 16);
}

// ---------------- weight casts: 9 jobs, optional gate-order row permutation ----------------
struct CastW { const float* src[9]; unsigned short* dst[9]; int n[9]; int L[9]; int perm[9]; };
__global__ void k_castw(CastW j) {
    const int a = blockIdx.y;
    const int i = blockIdx.x * 256 + threadIdx.x;
    if (i >= j.n[a]) return;
    const int L = j.L[a];
    const int r = i >> L, c = i & ((1 << L) - 1);
    const int dr = j.perm[a] ? ((r & 255) * 4 + (r >> 8)) : r;
    j.dst[a][(dr << L) | c] = f2bf(j.src[a][i]);
}
struct CastB { const float* src[4]; float* dst[4]; };
__global__ void k_castb(CastB j) {
    const int a = blockIdx.y;
    const int i = blockIdx.x * 256 + threadIdx.x;   // 0..1023
    j.dst[a][(i & 255) * 4 + (i >> 8)] = j.src[a][i];
}

// ---------------- gather: 5D f32 -> v_in bf16 [512*16][64] ----------------
__global__ void k_gather(const float* __restrict__ X, unsigned short* __restrict__ vin,
                         int sm, int sa, int sb) {
    const int seq = blockIdx.x;              // n*16+a
    const int n = seq >> 4, a = seq & 15;
    const size_t base = (size_t)(n >> 4) * 64 * 4096 + (size_t)sm * (n & 15) + (size_t)sa * a;
    for (int idx = threadIdx.x; idx < 1024; idx += 256) {
        const int c = idx & 63, b = idx >> 6;
        vin[((size_t)seq * 16 + b) * 64 + c] = f2bf(X[base + (size_t)c * 4096 + (size_t)sb * b]);
    }
}

// ---------------- GEMM: C[m][n](f16) = sum_k A[m][k]*W[n][k] + bias[n] ----------------
__global__ __launch_bounds__(256) void k_gemm(const unsigned short* __restrict__ A, int K,
        const unsigned short* __restrict__ W, const float* __restrict__ bias,
        __half* __restrict__ C, int ldc, int nvalid) {
    __shared__ unsigned short Alds[128 * 56];
    __shared__ unsigned short Blds[128 * 56];
    const int m0 = blockIdx.x * 128, n0 = blockIdx.y * 128;
    const int tid = threadIdx.x;
    const int lane = tid & 63, wid = tid >> 6;
    const int wr = wid >> 1, wc = wid & 1;
    const int fl = lane & 15, kk = (lane >> 4) * 8;
    f32x4 acc[4][4];
    #pragma unroll
    for (int mi = 0; mi < 4; mi++)
        #pragma unroll
        for (int ni = 0; ni < 4; ni++) { f32x4 z = {0.f,0.f,0.f,0.f}; acc[mi][ni] = z; }

    for (int k0 = 0; k0 < K; k0 += 32) {
        __syncthreads();
        #pragma unroll
        for (int h = 0; h < 2; h++) {
            const int cid = tid + h * 256;
            const int row = cid >> 2, c4 = cid & 3;
            *(u32x4*)&Alds[row * 56 + c4 * 8] = *(const u32x4*)(A + (size_t)(m0 + row) * K + k0 + c4 * 8);
            *(u32x4*)&Blds[row * 56 + c4 * 8] = *(const u32x4*)(W + (size_t)(n0 + row) * K + k0 + c4 * 8);
        }
        __syncthreads();
        bf16x8 af[4], bfb[4];
        #pragma unroll
        for (int i = 0; i < 4; i++) {
            af[i]  = *(const bf16x8*)&Alds[(wr * 64 + i * 16 + fl) * 56 + kk];
            bfb[i] = *(const bf16x8*)&Blds[(wc * 64 + i * 16 + fl) * 56 + kk];
        }
        #pragma unroll
        for (int mi = 0; mi < 4; mi++)
            #pragma unroll
            for (int ni = 0; ni < 4; ni++)
                acc[mi][ni] = __builtin_amdgcn_mfma_f32_16x16x32_bf16(af[mi], bfb[ni], acc[mi][ni], 0, 0, 0);
    }
    const int rl = (lane >> 4) * 4;
    #pragma unroll
    for (int ni = 0; ni < 4; ni++) {
        const int col = n0 + wc * 64 + ni * 16 + fl;
        if (col < nvalid) {
            const float bs = bias[col];
            #pragma unroll
            for (int mi = 0; mi < 4; mi++) {
                const int row = m0 + wr * 64 + mi * 16 + rl;
                #pragma unroll
                for (int j = 0; j < 4; j++)
                    C[(size_t)(row + j) * ldc + col] = __float2half(acc[mi][ni][j] + bs);
            }
        }
    }
}

// ---------------- LSTM scan v8: register weights + low-contention pair exchange ----------------
// grid (32, 2, 2): x = seq-tile, y = dir, z = kh (k-half). 512 threads (8 waves).
// Wave w owns gate cols [kh*512 + w*64, +64). Weights wown/wpar: 4nt x 4 bf16x8 each.
// Mailbox HX [slot][parity][512 u64]. Flags FLG: ONE u32 per slot at 256 B stride
// (padded -> no false sharing); single poller (tid 0) with RMW poll (v4-proven).
__global__ __launch_bounds__(512, 2) void k_scan(const __half* __restrict__ xw,
        const unsigned short* __restrict__ whh_f, const unsigned short* __restrict__ whh_b,
        unsigned short* __restrict__ out, int out_mode,
        unsigned long long* __restrict__ HX, unsigned int* __restrict__ FLG, int phase) {
    __shared__ __align__(16) char gbuf[512 * 40];      // gates f16 [512 local cols][20 s-slots]
    __shared__ __align__(16) char hbuf[16 * 512];      // h bf16 [16 s][256 k], XOR-swizzled
    const int tid = threadIdx.x;
    const int lane = tid & 63, w = tid >> 6;
    const int fl = lane & 15, fh = lane >> 4;
    const int st = blockIdx.x, dir = blockIdx.y, kh = blockIdx.z;
    const int seq0 = st * 16;
    const unsigned short* whh_k = (dir ? whh_b : whh_f) + (size_t)kh * 512 * 256;
    const __half* xwd = xw + (size_t)dir * (8192 * 1024);
    const int C0g = kh * 512 + w * 64;
    const int slot = ((dir * 32 + st) * 2 + kh);
    unsigned long long* hx_me = HX + (size_t)slot * 1024;
    const unsigned long long* hx_p = HX + (size_t)(slot ^ 1) * 1024;
    unsigned int* flg_me = FLG + slot * 64;          // 256 B stride -> own cache line
    unsigned int* flg_p  = FLG + (slot ^ 1) * 64;
    const unsigned int base = 16u * (unsigned int)phase;
    const int kOwnB = kh * 4;          // runtime — used in ADDRESSES only
    const int kParB = (1 - kh) * 4;    // runtime — used in ADDRESSES only

    // zero hbuf (h(-1) = 0, both halves)
    #pragma unroll
    for (int i = 0; i < 4; i++) ((unsigned int*)hbuf)[tid + i * 512] = 0u;

    // weights -> registers (once). kh only affects the load ADDRESS.
    bf16x8 wown[4][4], wpar[4][4];
    #pragma unroll
    for (int nt = 0; nt < 4; nt++) {
        const unsigned short* rowp = whh_k + (size_t)(w * 64 + nt * 16 + fl) * 256 + fh * 8;
        #pragma unroll
        for (int i = 0; i < 4; i++) {
            wown[nt][i] = *(const bf16x8*)(rowp + (kOwnB + i) * 32);
            wpar[nt][i] = *(const bf16x8*)(rowp + (kParB + i) * 32);
        }
    }

    const int li = lane & 15, ls = lane >> 4;
    const int khalf = w * 16 + li;               // k within this block's half [0,128)
    const int kglob = kh * 128 + khalf;
    float c_reg[4] = {0.f, 0.f, 0.f, 0.f};

    int tt = dir ? 15 : 0;
    const int tstep = dir ? -1 : 1;

    // prologue: xw C-operands for t=0 (elem (nt,j): seq row fh*4+j, col C0g+nt*16+fl)
    unsigned int xh[4][2];
    #pragma unroll
    for (int nt = 0; nt < 4; nt++)
        #pragma unroll
        for (int j2 = 0; j2 < 2; j2++) {
            const size_t b_ = ((size_t)(seq0 + fh * 4 + j2 * 2) * 16 + tt) * 1024 + C0g + nt * 16 + fl;
            const unsigned short h0 = __half_as_ushort(xwd[b_]);
            const unsigned short h1 = __half_as_ushort(xwd[b_ + 16 * 1024]);
            xh[nt][j2] = (unsigned int)h0 | ((unsigned int)h1 << 16);
        }

    __syncthreads();

    for (int t = 0; t < 16; t++) {
        // ---- copy-out h(t-1) own half (coalesced from hbuf) ----
        if (t > 0) {
            const int ttp = tt - tstep;
            const int s = tid >> 5, q = tid & 31;
            const int ba = (s * 512 + (kh * 128 + q * 4) * 2) ^ ((s & 7) << 4);
            const u32x2 hv = *(const u32x2*)(hbuf + ba);
            const size_t row = out_mode ? ((size_t)(seq0 + s) * 16 + ttp)
                                        : ((size_t)st * 256 + (size_t)ttp * 16 + s);
            *(u32x2*)(out + row * 512 + dir * 256 + kh * 128 + q * 4) = hv;
        }
        // ---- own-half A-frags + own-half MFMAs (no partner dependency) ----
        bf16x8 afr[4];
        #pragma unroll
        for (int i = 0; i < 4; i++) {
            const int ba = (fl * 512 + (kOwnB + i) * 64 + fh * 16) ^ ((fl & 7) << 4);
            afr[i] = *(const bf16x8*)(hbuf + ba);
        }
        f32x4 acc[4];
        #pragma unroll
        for (int nt = 0; nt < 4; nt++) {
            acc[nt][0] = __half2float(__ushort_as_half((unsigned short)(xh[nt][0] & 0xffff)));
            acc[nt][1] = __half2float(__ushort_as_half((unsigned short)(xh[nt][0] >> 16)));
            acc[nt][2] = __half2float(__ushort_as_half((unsigned short)(xh[nt][1] & 0xffff)));
            acc[nt][3] = __half2float(__ushort_as_half((unsigned short)(xh[nt][1] >> 16)));
            #pragma unroll
            for (int i = 0; i < 4; i++)
                acc[nt] = __builtin_amdgcn_mfma_f32_16x16x32_bf16(afr[i], wown[nt][i], acc[nt], 0, 0, 0);
        }
        // ---- xw prefetch for t+1 (flies during poll/pull) ----
        const int tn = (t < 15) ? tt + tstep : tt;
        #pragma unroll
        for (int nt = 0; nt < 4; nt++)
            #pragma unroll
            for (int j2 = 0; j2 < 2; j2++) {
                const size_t b_ = ((size_t)(seq0 + fh * 4 + j2 * 2) * 16 + tn) * 1024 + C0g + nt * 16 + fl;
                const unsigned short h0 = __half_as_ushort(xwd[b_]);
                const unsigned short h1 = __half_as_ushort(xwd[b_ + 16 * 1024]);
                xh[nt][j2] = (unsigned int)h0 | ((unsigned int)h1 << 16);
            }
        // ---- single-poller flag wait, then parallel sc1 pull of partner h(t-1) ----
        if (t > 0) {
            if (tid == 0) {
                const unsigned int want = base + (unsigned int)t;
                while (atomicAdd(flg_p, 0u) < want) __builtin_amdgcn_s_sleep(1);
            }
            __syncthreads();   // E1: flag confirmed for the whole block
            const unsigned long long pv =
                __hip_atomic_load(hx_p + (((t - 1) & 1) * 512 + tid), __ATOMIC_RELAXED, AGENT);
            const int kl = tid >> 2, sl0 = (tid & 3) * 4;
            const int kp = (1 - kh) * 128 + kl;
            #pragma unroll
            for (int e = 0; e < 4; e++) {
                const int s = sl0 + e;
                *(unsigned short*)(hbuf + ((s * 512 + kp * 2) ^ ((s & 7) << 4))) =
                    (unsigned short)(pv >> (16 * e));
            }
        }
        __syncthreads();   // E2: partner half in hbuf; all own-half reads done

        // ---- partner-half MFMAs ----
        #pragma unroll
        for (int i = 0; i < 4; i++) {
            const int ba = (fl * 512 + (kParB + i) * 64 + fh * 16) ^ ((fl & 7) << 4);
            afr[i] = *(const bf16x8*)(hbuf + ba);
        }
        #pragma unroll
        for (int nt = 0; nt < 4; nt++) {
            #pragma unroll
            for (int i = 0; i < 4; i++)
                acc[nt] = __builtin_amdgcn_mfma_f32_16x16x32_bf16(afr[i], wpar[nt][i], acc[nt], 0, 0, 0);
            const int coll = w * 64 + nt * 16 + fl;
            const unsigned int lo = (unsigned int)__half_as_ushort(__float2half(acc[nt][0])) |
                                    ((unsigned int)__half_as_ushort(__float2half(acc[nt][1])) << 16);
            const unsigned int hi = (unsigned int)__half_as_ushort(__float2half(acc[nt][2])) |
                                    ((unsigned int)__half_as_ushort(__float2half(acc[nt][3])) << 16);
            u32x2 pk = {lo, hi};
            *(u32x2*)(gbuf + coll * 40 + fh * 8) = pk;
        }

        // ---- nonlinearity (wave-local gbuf cols) ----
        float gv[4][4];
        const int colbase = w * 64 + 4 * li;
        #pragma unroll
        for (int g = 0; g < 4; g++) {
            const u32x2 a = *(const u32x2*)(gbuf + (colbase + g) * 40 + ls * 8);
            gv[g][0] = __half2float(__ushort_as_half((unsigned short)(a[0] & 0xffff)));
            gv[g][1] = __half2float(__ushort_as_half((unsigned short)(a[0] >> 16)));
            gv[g][2] = __half2float(__ushort_as_half((unsigned short)(a[1] & 0xffff)));
            gv[g][3] = __half2float(__ushort_as_half((unsigned short)(a[1] >> 16)));
        }
        unsigned long long hpack = 0ull;
        #pragma unroll
        for (int p2 = 0; p2 < 4; p2++) {
            const float ig = 1.f / (1.f + __expf(-gv[0][p2]));
            const float fg = 1.f / (1.f + __expf(-gv[1][p2]));
            const float e2 = __expf(2.f * gv[2][p2]);
            const float gg = 1.f - 2.f / (e2 + 1.f);
            const float og = 1.f / (1.f + __expf(-gv[3][p2]));
            const float c = fg * c_reg[p2] + ig * gg;
            c_reg[p2] = c;
            const float e2c = __expf(2.f * c);
            const float hv = og * (1.f - 2.f / (e2c + 1.f));
            const unsigned short hb = f2bf(hv);
            const int s = ls * 4 + p2;
            *(unsigned short*)(hbuf + ((s * 512 + kglob * 2) ^ ((s & 7) << 4))) = hb;
            hpack |= ((unsigned long long)hb) << (16 * p2);
        }

        // ---- publish own h(t) (relaxed sc1 stores; barrier F drains vmcnt) ----
        if (t < 15)
            __hip_atomic_store(hx_me + ((t & 1) * 512 + khalf * 4 + ls), hpack, __ATOMIC_RELAXED, AGENT);
        tt = tn;
        __syncthreads();   // F: hbuf(t) complete; vmcnt(0) drained -> publishes visible
        if (t < 15 && tid == 0)
            atomicExch(flg_me, base + (unsigned int)(t + 1));   // fire-and-forget
    }
    // epilogue: copy-out h(15) own half
    {
        const int s = tid >> 5, q = tid & 31;
        const int ba = (s * 512 + (kh * 128 + q * 4) * 2) ^ ((s & 7) << 4);
        const u32x2 hv = *(const u32x2*)(hbuf + ba);
        const size_t row = out_mode ? ((size_t)(seq0 + s) * 16 + tt)
                                    : ((size_t)st * 256 + (size_t)tt * 16 + s);
        *(u32x2*)(out + row * 512 + dir * 256 + kh * 128 + q * 4) = hv;
    }
}

// ---------------- conv2 scatter: f16 conv output -> 5D f32 ----------------
__global__ void k_scatter(const __half* __restrict__ conv, float* __restrict__ Xout,
                          int sm, int sa, int sb) {
    const int blk = blockIdx.x;
    const int n = blk >> 4, a = blk & 15;
    const size_t base = (size_t)(n >> 4) * 64 * 4096 + (size_t)sm * (n & 15) + (size_t)sa * a;
    for (int idx = threadIdx.x; idx < 1024; idx += 256) {
        const int b = idx & 15, o = idx >> 4;
        Xout[base + (size_t)o * 4096 + (size_t)sb * b] =
            __half2float(conv[((size_t)(n * 16 + b) * 16 + a) * 64 + o]);
    }
}

// ---------------- final conv3d 1x1x1 (f32 vector) ----------------
__global__ __launch_bounds__(256) void k_conv3(const float* __restrict__ X,
        const float* __restrict__ w, const float* __restrict__ bias, float* __restrict__ out) {
    __shared__ float xl[64 * 32];
    __shared__ float wl[64 * 64];
    const int bb = blockIdx.y;
    const int p0 = blockIdx.x * 32;
    const int tid = threadIdx.x;
    for (int i = tid; i < 64 * 32; i += 256) {
        const int c = i >> 5, pp = i & 31;
        xl[i] = X[((size_t)bb * 64 + c) * 4096 + p0 + pp];
    }
    for (int i = tid; i < 64 * 64; i += 256) wl[i] = w[i];
    __syncthreads();
    const int pp = tid & 31, og = tid >> 5;
    #pragma unroll
    for (int oj = 0; oj < 8; oj++) {
        const int o = og * 8 + oj;
        float acc = bias[o];
        #pragma unroll 16
        for (int c = 0; c < 64; c++) acc += xl[c * 32 + pp] * wl[o * 64 + c];
        out[((size_t)bb * 64 + o) * 4096 + p0 + pp] = acc;
    }
}

extern "C" void kernel_launch(void* const* d_in, const int* in_sizes, int n_in,
                              void* d_out, int out_size, void* d_ws, size_t ws_size,
                              hipStream_t stream) {
    (void)in_sizes; (void)n_in; (void)out_size; (void)ws_size;
    const float* x     = (const float*)d_in[0];
    const float* vwihf = (const float*)d_in[1];
    const float* vwhhf = (const float*)d_in[2];
    const float* vbf   = (const float*)d_in[3];
    const float* vwihb = (const float*)d_in[4];
    const float* vwhhb = (const float*)d_in[5];
    const float* vbb   = (const float*)d_in[6];
    const float* hwihf = (const float*)d_in[7];
    const float* hwhhf = (const float*)d_in[8];
    const float* hbf   = (const float*)d_in[9];
    const float* hwihb = (const float*)d_in[10];
    const float* hwhhb = (const float*)d_in[11];
    const float* hbb   = (const float*)d_in[12];
    const float* c2w   = (const float*)d_in[13];
    const float* c2b   = (const float*)d_in[14];
    const float* c3w   = (const float*)d_in[15];
    const float* c3b   = (const float*)d_in[16];

    char* p = (char*)d_ws;
    auto alloc = [&](size_t bytes) { char* r = p; p += (bytes + 255) & ~((size_t)255); return r; };
    unsigned short* bVWIHf = (unsigned short*)alloc((size_t)1024 * 64 * 2);
    unsigned short* bVWIHb = (unsigned short*)alloc((size_t)1024 * 64 * 2);
    unsigned short* bVWHHf = (unsigned short*)alloc((size_t)1024 * 256 * 2);
    unsigned short* bVWHHb = (unsigned short*)alloc((size_t)1024 * 256 * 2);
    unsigned short* bHWIHf = (unsigned short*)alloc((size_t)1024 * 512 * 2);
    unsigned short* bHWIHb = (unsigned short*)alloc((size_t)1024 * 512 * 2);
    unsigned short* bHWHHf = (unsigned short*)alloc((size_t)1024 * 256 * 2);
    unsigned short* bHWHHb = (unsigned short*)alloc((size_t)1024 * 256 * 2);
    unsigned short* bC2W   = (unsigned short*)alloc((size_t)128 * 512 * 2);
    float* pVBf = (float*)alloc(1024 * 4);
    float* pVBb = (float*)alloc(1024 * 4);
    float* pHBf = (float*)alloc(1024 * 4);
    float* pHBb = (float*)alloc(1024 * 4);
    unsigned long long* HX = (unsigned long long*)alloc((size_t)128 * 8192);  // [128 slots][2][512] u64
    unsigned int* FLG = (unsigned int*)alloc((size_t)128 * 256);              // 1 flag / 256 B line
    float* XA = (float*)alloc((size_t)524288 * 4);
    float* XB = (float*)alloc((size_t)524288 * 4);
    unsigned short* VIN = (unsigned short*)alloc((size_t)8192 * 64 * 2);
    __half* XW = (__half*)alloc((size_t)2 * 8192 * 1024 * 2);
    unsigned short* S_   = (unsigned short*)alloc((size_t)8192 * 512 * 2);
    unsigned short* HOUT = (unsigned short*)alloc((size_t)8192 * 512 * 2);
    __half* CONV = (__half*)VIN;   // reuse (dead by conv time)

    hipMemsetAsync(bC2W, 0, (size_t)128 * 512 * 2, stream);
    hipMemsetAsync(FLG, 0, (size_t)128 * 256, stream);   // epoch reset once per launch
    CastW cw;
    const float* srcs[9] = {vwihf, vwihb, vwhhf, vwhhb, hwihf, hwihb, hwhhf, hwhhb, c2w};
    unsigned short* dsts[9] = {bVWIHf, bVWIHb, bVWHHf, bVWHHb, bHWIHf, bHWIHb, bHWHHf, bHWHHb, bC2W};
    const int ns[9] = {65536, 65536, 262144, 262144, 524288, 524288, 262144, 262144, 32768};
    const int Ls[9] = {6, 6, 8, 8, 9, 9, 8, 8, 9};
    const int pm[9] = {1, 1, 1, 1, 1, 1, 1, 1, 0};
    for (int i = 0; i < 9; i++) { cw.src[i] = srcs[i]; cw.dst[i] = dsts[i]; cw.n[i] = ns[i]; cw.L[i] = Ls[i]; cw.perm[i] = pm[i]; }
    k_castw<<<dim3(2048, 9), 256, 0, stream>>>(cw);
    CastB cb;
    cb.src[0] = vbf; cb.dst[0] = pVBf;
    cb.src[1] = vbb; cb.dst[1] = pVBb;
    cb.src[2] = hbf; cb.dst[2] = pHBf;
    cb.src[3] = hbb; cb.dst[3] = pHBb;
    k_castb<<<dim3(4, 4), 256, 0, stream>>>(cb);

    const int SMs[3] = {256, 16, 1}, SAs[3] = {16, 256, 256}, SBs[3] = {1, 1, 16};
    for (int s = 0; s < 3; s++) {
        const float* Xin = (s == 0) ? x : ((s == 1) ? XA : XB);
        float* Xout = (s == 0) ? XA : ((s == 1) ? XB : XA);
        k_gather<<<512, 256, 0, stream>>>(Xin, VIN, SMs[s], SAs[s], SBs[s]);
        k_gemm<<<dim3(64, 8), 256, 0, stream>>>(VIN, 64, bVWIHf, pVBf, XW, 1024, 1024);
        k_gemm<<<dim3(64, 8), 256, 0, stream>>>(VIN, 64, bVWIHb, pVBb, XW + (size_t)8192 * 1024, 1024, 1024);
        k_scan<<<dim3(32, 2, 2), 512, 0, stream>>>(XW, bVWHHf, bVWHHb, S_, 0, HX, FLG, s * 2 + 0);
        k_gemm<<<dim3(64, 8), 256, 0, stream>>>(S_, 512, bHWIHf, pHBf, XW, 1024, 1024);
        k_gemm<<<dim3(64, 8), 256, 0, stream>>>(S_, 512, bHWIHb, pHBb, XW + (size_t)8192 * 1024, 1024, 1024);
        k_scan<<<dim3(32, 2, 2), 512, 0, stream>>>(XW, bHWHHf, bHWHHb, HOUT, 1, HX, FLG, s * 2 + 1);
        k_gemm<<<dim3(64, 1), 256, 0, stream>>>(HOUT, 512, bC2W, c2b, CONV, 64, 64);
        k_scatter<<<512, 256, 0, stream>>>(CONV, Xout, SMs[s], SAs[s], SBs[s]);
    }
    k_conv3<<<dim3(128, 2), 256, 0, stream>>>(XA, c3w, c3b, (float*)d_out);
}